// Round 2
// baseline (13400.763 us; speedup 1.0000x reference)
//
#include <hip/hip_runtime.h>
#include <hip/hip_bf16.h>

// B=4, T=1024, E=1024, H=16, D=64, P=257.  Slot s = b*16+h (64 slots).
// Torch view(B*H)->(H,B) quirk: score slot m reads rel-K table of slot
// pm=(m&15)*4+(m>>4); attn of slot m feeds the w2 output of slot
// m2=(m&3)*16+(m>>2)  (pm(m2)==m).
// Workspace: qs/ks/vs/c1/c2 = 5 x 4M floats = 80 MB total.

// ---------------------------------------------------------------------------
// K1: fused QKV projection.  q/k/v[n,e] = hs[n,:]·W[e,:] + b[e]; q scaled 1/8.
// Output in slot layout: out[((b*16+h)*1024 + t)*64 + d].
// ---------------------------------------------------------------------------
__global__ __launch_bounds__(256) void k_qkv(
    const float* __restrict__ hs,
    const float* __restrict__ Wq, const float* __restrict__ bq,
    const float* __restrict__ Wk, const float* __restrict__ bk,
    const float* __restrict__ Wv, const float* __restrict__ bv,
    float* __restrict__ qs, float* __restrict__ ks, float* __restrict__ vs)
{
    __shared__ float sA[16][132];
    __shared__ float sB[16][132];
    const int tid = threadIdx.x;
    const int tx = tid & 15, ty = tid >> 4;
    const int eb = blockIdx.x * 128;
    const int nb = blockIdx.y * 128;
    const int z = blockIdx.z;
    const float* W    = (z == 0) ? Wq : (z == 1) ? Wk : Wv;
    const float* bias = (z == 0) ? bq : (z == 1) ? bk : bv;
    float* out        = (z == 0) ? qs : (z == 1) ? ks : vs;
    const float scale = (z == 0) ? 0.125f : 1.0f;

    float acc[8][8];
    #pragma unroll
    for (int i = 0; i < 8; ++i)
        #pragma unroll
        for (int j = 0; j < 8; ++j) acc[i][j] = 0.0f;

    for (int kb = 0; kb < 1024; kb += 16) {
        #pragma unroll
        for (int l = 0; l < 2; ++l) {
            int fid = tid + l * 256;
            int r = fid >> 2, c4 = (fid & 3) * 4;
            float4 av = *(const float4*)(hs + (size_t)(nb + r) * 1024 + kb + c4);
            sA[c4+0][r] = av.x; sA[c4+1][r] = av.y; sA[c4+2][r] = av.z; sA[c4+3][r] = av.w;
            float4 wv = *(const float4*)(W + (size_t)(eb + r) * 1024 + kb + c4);
            sB[c4+0][r] = wv.x; sB[c4+1][r] = wv.y; sB[c4+2][r] = wv.z; sB[c4+3][r] = wv.w;
        }
        __syncthreads();
        #pragma unroll
        for (int kk = 0; kk < 16; ++kk) {
            float a[8], b[8];
            *(float4*)&a[0] = *(const float4*)&sA[kk][ty*8];
            *(float4*)&a[4] = *(const float4*)&sA[kk][ty*8+4];
            *(float4*)&b[0] = *(const float4*)&sB[kk][tx*8];
            *(float4*)&b[4] = *(const float4*)&sB[kk][tx*8+4];
            #pragma unroll
            for (int i = 0; i < 8; ++i)
                #pragma unroll
                for (int j = 0; j < 8; ++j) acc[i][j] += a[i] * b[j];
        }
        __syncthreads();
    }
    float bb[8];
    *(float4*)&bb[0] = *(const float4*)(bias + eb + tx*8);
    *(float4*)&bb[4] = *(const float4*)(bias + eb + tx*8 + 4);
    #pragma unroll
    for (int i = 0; i < 8; ++i) {
        int n = nb + ty*8 + i;
        int bidx = n >> 10, t = n & 1023;
        #pragma unroll
        for (int jj = 0; jj < 2; ++jj) {
            int e0 = eb + tx*8 + jj*4;
            int h = e0 >> 6, d = e0 & 63;
            float4 o;
            o.x = (acc[i][jj*4+0] + bb[jj*4+0]) * scale;
            o.y = (acc[i][jj*4+1] + bb[jj*4+1]) * scale;
            o.z = (acc[i][jj*4+2] + bb[jj*4+2]) * scale;
            o.w = (acc[i][jj*4+3] + bb[jj*4+3]) * scale;
            *(float4*)(out + (size_t)((bidx*16 + h) * 1024 + t) * 64 + d) = o;
        }
    }
}

// ---------------------------------------------------------------------------
// K2: fused attention.  Per block: slot m, 16 q-rows.
//   A) R-slice: sR[q][j] = Q[pm][q0+q]·relk[j]        (j in [0,257))
//   B) scores[q][k] = Q[m][q]·K[m][k] + sR[q][clip(q-k)+128]   (regs, 64/thr)
//   C) softmax over k (64-lane shuffles)
//   D) w1 = P·V[m] -> c1 slot m;  banded-A built into sR (reused)
//   E) w2 = Aband·relv -> c2 slot m2
// ---------------------------------------------------------------------------
__global__ __launch_bounds__(256) void k_fused(
    const float* __restrict__ qs, const float* __restrict__ ks,
    const float* __restrict__ vs, const float* __restrict__ relk,
    const float* __restrict__ relv,
    float* __restrict__ c1, float* __restrict__ c2)
{
    __shared__ float sQ[16][68];     //  4352 B
    __shared__ float sKV[128][68];   // 34816 B  (Qpm / K / V / relv halves)
    __shared__ float sR[16][257];    // 16448 B  (R-slice, then Aband)
    __shared__ float sP[16][132];    //  8448 B  -> total 64064 B
    const int tid = threadIdx.x;
    const int m = blockIdx.y;
    const int q0 = blockIdx.x * 16;
    const int pm = (m & 15) * 4 + (m >> 4);
    const int m2 = (m & 3) * 16 + (m >> 2);

    // ---- Phase A: Q tiles + R-slice ----
    {
        int r = tid >> 4, c4 = (tid & 15) * 4;
        *(float4*)&sQ[r][c4]  = *(const float4*)(qs + (size_t)(m*1024  + q0 + r) * 64 + c4);
        *(float4*)&sKV[r][c4] = *(const float4*)(qs + (size_t)(pm*1024 + q0 + r) * 64 + c4);
    }
    __syncthreads();
    {
        const int q = tid & 15;
        float4 qv[16];
        #pragma unroll
        for (int d4 = 0; d4 < 16; ++d4) qv[d4] = *(const float4*)&sKV[q][d4*4];
        for (int j = tid >> 4; j < 257; j += 16) {
            float a = 0.0f;
            #pragma unroll
            for (int d4 = 0; d4 < 16; ++d4) {
                float4 rv = *(const float4*)(relk + j*64 + d4*4);
                a += qv[d4].x*rv.x + qv[d4].y*rv.y + qv[d4].z*rv.z + qv[d4].w*rv.w;
            }
            sR[q][j] = a;
        }
    }
    __syncthreads();

    // ---- Phase B: scores ----
    const int ty = tid >> 6, u = tid & 63;
    float sc[4][16];
    for (int kt = 0; kt < 8; ++kt) {
        #pragma unroll
        for (int l = 0; l < 8; ++l) {
            int f = tid + l * 256;
            int r = f >> 4, c4 = (f & 15) * 4;
            *(float4*)&sKV[r][c4] = *(const float4*)(ks + (size_t)(m*1024 + kt*128 + r) * 64 + c4);
        }
        __syncthreads();
        float a0[4], a1[4];
        #pragma unroll
        for (int i = 0; i < 4; ++i) { a0[i] = 0.0f; a1[i] = 0.0f; }
        #pragma unroll
        for (int d4 = 0; d4 < 16; ++d4) {
            float4 k0 = *(const float4*)&sKV[u][d4*4];
            float4 k1 = *(const float4*)&sKV[u + 64][d4*4];
            #pragma unroll
            for (int i = 0; i < 4; ++i) {
                float4 qv4 = *(const float4*)&sQ[ty*4 + i][d4*4];
                a0[i] += qv4.x*k0.x + qv4.y*k0.y + qv4.z*k0.z + qv4.w*k0.w;
                a1[i] += qv4.x*k1.x + qv4.y*k1.y + qv4.z*k1.z + qv4.w*k1.w;
            }
        }
        #pragma unroll
        for (int i = 0; i < 4; ++i) {
            int qg = q0 + ty*4 + i;
            #pragma unroll
            for (int j = 0; j < 2; ++j) {
                int kg = kt*128 + u + 64*j;
                int dist = qg - kg;
                int jd = dist < -128 ? 0 : (dist > 128 ? 256 : dist + 128);
                sc[i][kt*2 + j] = ((j == 0) ? a0[i] : a1[i]) + sR[ty*4 + i][jd];
            }
        }
        __syncthreads();
    }

    // ---- Phase C: softmax (rows ty*4..ty*4+3 owned by wave ty) ----
    #pragma unroll
    for (int i = 0; i < 4; ++i) {
        float mx = -1e30f;
        #pragma unroll
        for (int t2 = 0; t2 < 16; ++t2) mx = fmaxf(mx, sc[i][t2]);
        #pragma unroll
        for (int off = 1; off < 64; off <<= 1) mx = fmaxf(mx, __shfl_xor(mx, off, 64));
        float sum = 0.0f;
        #pragma unroll
        for (int t2 = 0; t2 < 16; ++t2) {
            float e = exp2f((sc[i][t2] - mx) * 1.44269504f);
            sc[i][t2] = e; sum += e;
        }
        #pragma unroll
        for (int off = 1; off < 64; off <<= 1) sum += __shfl_xor(sum, off, 64);
        float inv = 1.0f / sum;
        #pragma unroll
        for (int t2 = 0; t2 < 16; ++t2) sc[i][t2] *= inv;
    }

    // ---- Phase D: zero Aband, band scatter, w1 = P·V ----
    for (int idx = tid; idx < 16*257; idx += 256) ((float*)sR)[idx] = 0.0f;
    __syncthreads();
    {
        float e0[4] = {0,0,0,0}, e1[4] = {0,0,0,0};
        #pragma unroll
        for (int i = 0; i < 4; ++i) {
            int qg = q0 + ty*4 + i;
            #pragma unroll
            for (int t2 = 0; t2 < 16; ++t2) {
                int kg = (t2 >> 1) * 128 + u + 64 * (t2 & 1);
                int dist = qg - kg;
                float v = sc[i][t2];
                if (dist >= 128)        e1[i] += v;
                else if (dist <= -128)  e0[i] += v;
                else                    sR[ty*4 + i][dist + 128] = v;
            }
        }
        #pragma unroll
        for (int i = 0; i < 4; ++i) {
            #pragma unroll
            for (int off = 1; off < 64; off <<= 1) {
                e0[i] += __shfl_xor(e0[i], off, 64);
                e1[i] += __shfl_xor(e1[i], off, 64);
            }
        }
        if (u == 0) {
            #pragma unroll
            for (int i = 0; i < 4; ++i) {
                sR[ty*4 + i][0]   = e0[i];
                sR[ty*4 + i][256] = e1[i];
            }
        }
    }

    const int qw = tid >> 4, dw = (tid & 15) * 4;
    float w1a[4] = {0,0,0,0};
    for (int kt = 0; kt < 8; ++kt) {
        #pragma unroll
        for (int l = 0; l < 8; ++l) {
            int f = tid + l * 256;
            int r = f >> 4, c4 = (f & 15) * 4;
            *(float4*)&sKV[r][c4] = *(const float4*)(vs + (size_t)(m*1024 + kt*128 + r) * 64 + c4);
        }
        #pragma unroll
        for (int i = 0; i < 4; ++i) {
            sP[ty*4 + i][u]      = sc[i][kt*2 + 0];
            sP[ty*4 + i][u + 64] = sc[i][kt*2 + 1];
        }
        __syncthreads();
        for (int kk = 0; kk < 128; kk += 4) {
            float4 p4 = *(const float4*)&sP[qw][kk];
            float4 v0 = *(const float4*)&sKV[kk+0][dw];
            float4 v1 = *(const float4*)&sKV[kk+1][dw];
            float4 v2 = *(const float4*)&sKV[kk+2][dw];
            float4 v3 = *(const float4*)&sKV[kk+3][dw];
            w1a[0] += p4.x*v0.x + p4.y*v1.x + p4.z*v2.x + p4.w*v3.x;
            w1a[1] += p4.x*v0.y + p4.y*v1.y + p4.z*v2.y + p4.w*v3.y;
            w1a[2] += p4.x*v0.z + p4.y*v1.z + p4.z*v2.z + p4.w*v3.z;
            w1a[3] += p4.x*v0.w + p4.y*v1.w + p4.z*v2.w + p4.w*v3.w;
        }
        __syncthreads();
    }

    // ---- Phase E: w2 = Aband·relv (relv staged in LDS halves) ----
    float w2a[4] = {0,0,0,0};
    for (int half = 0; half < 2; ++half) {
        #pragma unroll
        for (int l = 0; l < 8; ++l) {
            int f = tid + l * 256;
            int r = f >> 4, c4 = (f & 15) * 4;
            *(float4*)&sKV[r][c4] = *(const float4*)(relv + (half*128 + r) * 64 + c4);
        }
        __syncthreads();
        for (int j = 0; j < 128; ++j) {
            float a = sR[qw][half*128 + j];
            float4 rv = *(const float4*)&sKV[j][dw];
            w2a[0] += a*rv.x; w2a[1] += a*rv.y; w2a[2] += a*rv.z; w2a[3] += a*rv.w;
        }
        __syncthreads();
    }
    {
        float a = sR[qw][256];
        float4 rv = *(const float4*)(relv + 256*64 + dw);
        w2a[0] += a*rv.x; w2a[1] += a*rv.y; w2a[2] += a*rv.z; w2a[3] += a*rv.w;
    }

    const int b1 = m >> 4,  h1 = m & 15;
    const int b2 = m2 >> 4, h2 = m2 & 15;
    *(float4*)(c1 + (size_t)(b1*1024 + q0 + qw) * 1024 + h1*64 + dw) =
        make_float4(w1a[0], w1a[1], w1a[2], w1a[3]);
    *(float4*)(c2 + (size_t)(b2*1024 + q0 + qw) * 1024 + h2*64 + dw) =
        make_float4(w2a[0], w2a[1], w2a[2], w2a[3]);
}

// ---------------------------------------------------------------------------
// K3: out = (c1+c2) @ Wo^T + bo   (4096x1024x1024)
// ---------------------------------------------------------------------------
__global__ __launch_bounds__(256) void k_oproj(
    const float* __restrict__ c1, const float* __restrict__ c2,
    const float* __restrict__ Wo, const float* __restrict__ bo,
    float* __restrict__ outp)
{
    __shared__ float sA[16][132];
    __shared__ float sB[16][132];
    const int tid = threadIdx.x;
    const int tx = tid & 15, ty = tid >> 4;
    const int eb = blockIdx.x * 128;
    const int nb = blockIdx.y * 128;

    float acc[8][8];
    #pragma unroll
    for (int i = 0; i < 8; ++i)
        #pragma unroll
        for (int j = 0; j < 8; ++j) acc[i][j] = 0.0f;

    for (int kb = 0; kb < 1024; kb += 16) {
        #pragma unroll
        for (int l = 0; l < 2; ++l) {
            int fid = tid + l * 256;
            int r = fid >> 2, c4 = (fid & 3) * 4;
            size_t aoff = (size_t)(nb + r) * 1024 + kb + c4;
            float4 a1 = *(const float4*)(c1 + aoff);
            float4 a2 = *(const float4*)(c2 + aoff);
            sA[c4+0][r] = a1.x + a2.x; sA[c4+1][r] = a1.y + a2.y;
            sA[c4+2][r] = a1.z + a2.z; sA[c4+3][r] = a1.w + a2.w;
            float4 wv = *(const float4*)(Wo + (size_t)(eb + r) * 1024 + kb + c4);
            sB[c4+0][r] = wv.x; sB[c4+1][r] = wv.y; sB[c4+2][r] = wv.z; sB[c4+3][r] = wv.w;
        }
        __syncthreads();
        #pragma unroll
        for (int kk = 0; kk < 16; ++kk) {
            float a[8], b[8];
            *(float4*)&a[0] = *(const float4*)&sA[kk][ty*8];
            *(float4*)&a[4] = *(const float4*)&sA[kk][ty*8+4];
            *(float4*)&b[0] = *(const float4*)&sB[kk][tx*8];
            *(float4*)&b[4] = *(const float4*)&sB[kk][tx*8+4];
            #pragma unroll
            for (int i = 0; i < 8; ++i)
                #pragma unroll
                for (int j = 0; j < 8; ++j) acc[i][j] += a[i] * b[j];
        }
        __syncthreads();
    }
    float bb[8];
    *(float4*)&bb[0] = *(const float4*)(bo + eb + tx*8);
    *(float4*)&bb[4] = *(const float4*)(bo + eb + tx*8 + 4);
    #pragma unroll
    for (int i = 0; i < 8; ++i) {
        int n = nb + ty*8 + i;
        #pragma unroll
        for (int jj = 0; jj < 2; ++jj) {
            float4 o;
            o.x = acc[i][jj*4+0] + bb[jj*4+0];
            o.y = acc[i][jj*4+1] + bb[jj*4+1];
            o.z = acc[i][jj*4+2] + bb[jj*4+2];
            o.w = acc[i][jj*4+3] + bb[jj*4+3];
            *(float4*)(outp + (size_t)n * 1024 + eb + tx*8 + jj*4) = o;
        }
    }
}

// ---------------------------------------------------------------------------
extern "C" void kernel_launch(void* const* d_in, const int* in_sizes, int n_in,
                              void* d_out, int out_size, void* d_ws, size_t ws_size,
                              hipStream_t stream) {
    const float* hs   = (const float*)d_in[0];
    const float* Wq   = (const float*)d_in[1];
    const float* bq   = (const float*)d_in[2];
    const float* Wk   = (const float*)d_in[3];
    const float* bk   = (const float*)d_in[4];
    const float* Wv   = (const float*)d_in[5];
    const float* bv   = (const float*)d_in[6];
    const float* Wo   = (const float*)d_in[7];
    const float* bo   = (const float*)d_in[8];
    const float* relk = (const float*)d_in[9];
    const float* relv = (const float*)d_in[10];
    float* out = (float*)d_out;

    // Workspace: 5 x 4,194,304 floats = 80 MB.
    float* ws = (float*)d_ws;
    float* qs = ws;
    float* ks = ws + 4194304;
    float* vs = ws + 8388608;
    float* c1 = ws + 12582912;
    float* c2 = ws + 16777216;

    k_qkv  <<<dim3(8, 32, 3), 256, 0, stream>>>(hs, Wq, bq, Wk, bk, Wv, bv, qs, ks, vs);
    k_fused<<<dim3(64, 64),   256, 0, stream>>>(qs, ks, vs, relk, relv, c1, c2);
    k_oproj<<<dim3(8, 32),    256, 0, stream>>>(c1, c2, Wo, bo, out);
}

// Round 3
// 11997.824 us; speedup vs baseline: 1.1169x; 1.1169x over previous
//
#include <hip/hip_runtime.h>
#include <hip/hip_bf16.h>

// B=4, T=1024, E=1024, H=16, D=64, P=257.  Slot s = b*16+h (64 slots).
// Torch view(B*H)->(H,B) quirk: score slot m reads rel-K table of slot
// pm=(m&15)*4+(m>>4); attn of slot m feeds the w2 output of slot
// m2=(m&3)*16+(m>>2)  (pm(m2)==m).
// Workspace: qs/ks/vs/c1/c2 = 5 x 4M floats = 80 MB total.

// ---------------------------------------------------------------------------
// K1: fused QKV projection.  q/k/v[n,e] = hs[n,:]·W[e,:] + b[e]; q scaled 1/8.
// Output in slot layout: out[((b*16+h)*1024 + t)*64 + d].
// ---------------------------------------------------------------------------
__global__ __launch_bounds__(256) void k_qkv(
    const float* __restrict__ hs,
    const float* __restrict__ Wq, const float* __restrict__ bq,
    const float* __restrict__ Wk, const float* __restrict__ bk,
    const float* __restrict__ Wv, const float* __restrict__ bv,
    float* __restrict__ qs, float* __restrict__ ks, float* __restrict__ vs)
{
    __shared__ float sA[16][132];
    __shared__ float sB[16][132];
    const int tid = threadIdx.x;
    const int tx = tid & 15, ty = tid >> 4;
    const int eb = blockIdx.x * 128;
    const int nb = blockIdx.y * 128;
    const int z = blockIdx.z;
    const float* W    = (z == 0) ? Wq : (z == 1) ? Wk : Wv;
    const float* bias = (z == 0) ? bq : (z == 1) ? bk : bv;
    float* out        = (z == 0) ? qs : (z == 1) ? ks : vs;
    const float scale = (z == 0) ? 0.125f : 1.0f;

    float acc[8][8];
    #pragma unroll
    for (int i = 0; i < 8; ++i)
        #pragma unroll
        for (int j = 0; j < 8; ++j) acc[i][j] = 0.0f;

    for (int kb = 0; kb < 1024; kb += 16) {
        #pragma unroll
        for (int l = 0; l < 2; ++l) {
            int fid = tid + l * 256;
            int r = fid >> 2, c4 = (fid & 3) * 4;
            float4 av = *(const float4*)(hs + (size_t)(nb + r) * 1024 + kb + c4);
            sA[c4+0][r] = av.x; sA[c4+1][r] = av.y; sA[c4+2][r] = av.z; sA[c4+3][r] = av.w;
            float4 wv = *(const float4*)(W + (size_t)(eb + r) * 1024 + kb + c4);
            sB[c4+0][r] = wv.x; sB[c4+1][r] = wv.y; sB[c4+2][r] = wv.z; sB[c4+3][r] = wv.w;
        }
        __syncthreads();
        #pragma unroll
        for (int kk = 0; kk < 16; ++kk) {
            float a[8], b[8];
            *(float4*)&a[0] = *(const float4*)&sA[kk][ty*8];
            *(float4*)&a[4] = *(const float4*)&sA[kk][ty*8+4];
            *(float4*)&b[0] = *(const float4*)&sB[kk][tx*8];
            *(float4*)&b[4] = *(const float4*)&sB[kk][tx*8+4];
            #pragma unroll
            for (int i = 0; i < 8; ++i)
                #pragma unroll
                for (int j = 0; j < 8; ++j) acc[i][j] += a[i] * b[j];
        }
        __syncthreads();
    }
    float bb[8];
    *(float4*)&bb[0] = *(const float4*)(bias + eb + tx*8);
    *(float4*)&bb[4] = *(const float4*)(bias + eb + tx*8 + 4);
    #pragma unroll
    for (int i = 0; i < 8; ++i) {
        int n = nb + ty*8 + i;
        int bidx = n >> 10, t = n & 1023;
        #pragma unroll
        for (int jj = 0; jj < 2; ++jj) {
            int e0 = eb + tx*8 + jj*4;
            int h = e0 >> 6, d = e0 & 63;
            float4 o;
            o.x = (acc[i][jj*4+0] + bb[jj*4+0]) * scale;
            o.y = (acc[i][jj*4+1] + bb[jj*4+1]) * scale;
            o.z = (acc[i][jj*4+2] + bb[jj*4+2]) * scale;
            o.w = (acc[i][jj*4+3] + bb[jj*4+3]) * scale;
            *(float4*)(out + (size_t)((bidx*16 + h) * 1024 + t) * 64 + d) = o;
        }
    }
}

// ---------------------------------------------------------------------------
// K2: fused attention.  Per block: slot m, 16 q-rows.
// NOTE: kt loops MUST be fully unrolled — sc[][] indexed by kt; a dynamic
// index demotes sc to scratch (R2: 15.9 GB spill writes, 12.8 ms kernel).
// ---------------------------------------------------------------------------
__global__ __launch_bounds__(256) void k_fused(
    const float* __restrict__ qs, const float* __restrict__ ks,
    const float* __restrict__ vs, const float* __restrict__ relk,
    const float* __restrict__ relv,
    float* __restrict__ c1, float* __restrict__ c2)
{
    __shared__ float sQ[16][68];     //  4352 B
    __shared__ float sKV[128][68];   // 34816 B  (Qpm / K / V / relv halves)
    __shared__ float sR[16][257];    // 16448 B  (R-slice, then Aband)
    __shared__ float sP[16][132];    //  8448 B  -> total 64064 B
    const int tid = threadIdx.x;
    const int m = blockIdx.y;
    const int q0 = blockIdx.x * 16;
    const int pm = (m & 15) * 4 + (m >> 4);
    const int m2 = (m & 3) * 16 + (m >> 2);

    // ---- Phase A: Q tiles + R-slice ----
    {
        int r = tid >> 4, c4 = (tid & 15) * 4;
        *(float4*)&sQ[r][c4]  = *(const float4*)(qs + (size_t)(m*1024  + q0 + r) * 64 + c4);
        *(float4*)&sKV[r][c4] = *(const float4*)(qs + (size_t)(pm*1024 + q0 + r) * 64 + c4);
    }
    __syncthreads();
    {
        const int q = tid & 15;
        float4 qv[16];
        #pragma unroll
        for (int d4 = 0; d4 < 16; ++d4) qv[d4] = *(const float4*)&sKV[q][d4*4];
        for (int j = tid >> 4; j < 257; j += 16) {
            float a = 0.0f;
            #pragma unroll
            for (int d4 = 0; d4 < 16; ++d4) {
                float4 rv = *(const float4*)(relk + j*64 + d4*4);
                a += qv[d4].x*rv.x + qv[d4].y*rv.y + qv[d4].z*rv.z + qv[d4].w*rv.w;
            }
            sR[q][j] = a;
        }
    }
    __syncthreads();

    // ---- Phase B: scores ----
    const int ty = tid >> 6, u = tid & 63;
    float sc[4][16];
    #pragma unroll
    for (int kt = 0; kt < 8; ++kt) {
        #pragma unroll
        for (int l = 0; l < 8; ++l) {
            int f = tid + l * 256;
            int r = f >> 4, c4 = (f & 15) * 4;
            *(float4*)&sKV[r][c4] = *(const float4*)(ks + (size_t)(m*1024 + kt*128 + r) * 64 + c4);
        }
        __syncthreads();
        float a0[4], a1[4];
        #pragma unroll
        for (int i = 0; i < 4; ++i) { a0[i] = 0.0f; a1[i] = 0.0f; }
        #pragma unroll
        for (int d4 = 0; d4 < 16; ++d4) {
            float4 k0 = *(const float4*)&sKV[u][d4*4];
            float4 k1 = *(const float4*)&sKV[u + 64][d4*4];
            #pragma unroll
            for (int i = 0; i < 4; ++i) {
                float4 qv4 = *(const float4*)&sQ[ty*4 + i][d4*4];
                a0[i] += qv4.x*k0.x + qv4.y*k0.y + qv4.z*k0.z + qv4.w*k0.w;
                a1[i] += qv4.x*k1.x + qv4.y*k1.y + qv4.z*k1.z + qv4.w*k1.w;
            }
        }
        #pragma unroll
        for (int i = 0; i < 4; ++i) {
            int qg = q0 + ty*4 + i;
            #pragma unroll
            for (int j = 0; j < 2; ++j) {
                int kg = kt*128 + u + 64*j;
                int dist = qg - kg;
                int jd = dist < -128 ? 0 : (dist > 128 ? 256 : dist + 128);
                sc[i][kt*2 + j] = ((j == 0) ? a0[i] : a1[i]) + sR[ty*4 + i][jd];
            }
        }
        __syncthreads();
    }

    // ---- Phase C: softmax (rows ty*4..ty*4+3 owned by wave ty) ----
    #pragma unroll
    for (int i = 0; i < 4; ++i) {
        float mx = -1e30f;
        #pragma unroll
        for (int t2 = 0; t2 < 16; ++t2) mx = fmaxf(mx, sc[i][t2]);
        #pragma unroll
        for (int off = 1; off < 64; off <<= 1) mx = fmaxf(mx, __shfl_xor(mx, off, 64));
        float sum = 0.0f;
        #pragma unroll
        for (int t2 = 0; t2 < 16; ++t2) {
            float e = exp2f((sc[i][t2] - mx) * 1.44269504f);
            sc[i][t2] = e; sum += e;
        }
        #pragma unroll
        for (int off = 1; off < 64; off <<= 1) sum += __shfl_xor(sum, off, 64);
        float inv = 1.0f / sum;
        #pragma unroll
        for (int t2 = 0; t2 < 16; ++t2) sc[i][t2] *= inv;
    }

    // ---- Phase D: zero Aband, band scatter, w1 = P·V ----
    for (int idx = tid; idx < 16*257; idx += 256) ((float*)sR)[idx] = 0.0f;
    __syncthreads();
    {
        float e0[4] = {0,0,0,0}, e1[4] = {0,0,0,0};
        #pragma unroll
        for (int i = 0; i < 4; ++i) {
            int qg = q0 + ty*4 + i;
            #pragma unroll
            for (int t2 = 0; t2 < 16; ++t2) {
                int kg = (t2 >> 1) * 128 + u + 64 * (t2 & 1);
                int dist = qg - kg;
                float v = sc[i][t2];
                if (dist >= 128)        e1[i] += v;
                else if (dist <= -128)  e0[i] += v;
                else                    sR[ty*4 + i][dist + 128] = v;
            }
        }
        #pragma unroll
        for (int i = 0; i < 4; ++i) {
            #pragma unroll
            for (int off = 1; off < 64; off <<= 1) {
                e0[i] += __shfl_xor(e0[i], off, 64);
                e1[i] += __shfl_xor(e1[i], off, 64);
            }
        }
        if (u == 0) {
            #pragma unroll
            for (int i = 0; i < 4; ++i) {
                sR[ty*4 + i][0]   = e0[i];
                sR[ty*4 + i][256] = e1[i];
            }
        }
    }

    const int qw = tid >> 4, dw = (tid & 15) * 4;
    float w1a[4] = {0,0,0,0};
    #pragma unroll
    for (int kt = 0; kt < 8; ++kt) {
        #pragma unroll
        for (int l = 0; l < 8; ++l) {
            int f = tid + l * 256;
            int r = f >> 4, c4 = (f & 15) * 4;
            *(float4*)&sKV[r][c4] = *(const float4*)(vs + (size_t)(m*1024 + kt*128 + r) * 64 + c4);
        }
        #pragma unroll
        for (int i = 0; i < 4; ++i) {
            sP[ty*4 + i][u]      = sc[i][kt*2 + 0];
            sP[ty*4 + i][u + 64] = sc[i][kt*2 + 1];
        }
        __syncthreads();
        for (int kk = 0; kk < 128; kk += 4) {
            float4 p4 = *(const float4*)&sP[qw][kk];
            float4 v0 = *(const float4*)&sKV[kk+0][dw];
            float4 v1 = *(const float4*)&sKV[kk+1][dw];
            float4 v2 = *(const float4*)&sKV[kk+2][dw];
            float4 v3 = *(const float4*)&sKV[kk+3][dw];
            w1a[0] += p4.x*v0.x + p4.y*v1.x + p4.z*v2.x + p4.w*v3.x;
            w1a[1] += p4.x*v0.y + p4.y*v1.y + p4.z*v2.y + p4.w*v3.y;
            w1a[2] += p4.x*v0.z + p4.y*v1.z + p4.z*v2.z + p4.w*v3.z;
            w1a[3] += p4.x*v0.w + p4.y*v1.w + p4.z*v2.w + p4.w*v3.w;
        }
        __syncthreads();
    }

    // ---- Phase E: w2 = Aband·relv (relv staged in LDS halves) ----
    float w2a[4] = {0,0,0,0};
    #pragma unroll
    for (int half = 0; half < 2; ++half) {
        #pragma unroll
        for (int l = 0; l < 8; ++l) {
            int f = tid + l * 256;
            int r = f >> 4, c4 = (f & 15) * 4;
            *(float4*)&sKV[r][c4] = *(const float4*)(relv + (half*128 + r) * 64 + c4);
        }
        __syncthreads();
        for (int j = 0; j < 128; ++j) {
            float a = sR[qw][half*128 + j];
            float4 rv = *(const float4*)&sKV[j][dw];
            w2a[0] += a*rv.x; w2a[1] += a*rv.y; w2a[2] += a*rv.z; w2a[3] += a*rv.w;
        }
        __syncthreads();
    }
    {
        float a = sR[qw][256];
        float4 rv = *(const float4*)(relv + 256*64 + dw);
        w2a[0] += a*rv.x; w2a[1] += a*rv.y; w2a[2] += a*rv.z; w2a[3] += a*rv.w;
    }

    const int b1 = m >> 4,  h1 = m & 15;
    const int b2 = m2 >> 4, h2 = m2 & 15;
    *(float4*)(c1 + (size_t)(b1*1024 + q0 + qw) * 1024 + h1*64 + dw) =
        make_float4(w1a[0], w1a[1], w1a[2], w1a[3]);
    *(float4*)(c2 + (size_t)(b2*1024 + q0 + qw) * 1024 + h2*64 + dw) =
        make_float4(w2a[0], w2a[1], w2a[2], w2a[3]);
}

// ---------------------------------------------------------------------------
// K3: out = (c1+c2) @ Wo^T + bo   (4096x1024x1024)
// ---------------------------------------------------------------------------
__global__ __launch_bounds__(256) void k_oproj(
    const float* __restrict__ c1, const float* __restrict__ c2,
    const float* __restrict__ Wo, const float* __restrict__ bo,
    float* __restrict__ outp)
{
    __shared__ float sA[16][132];
    __shared__ float sB[16][132];
    const int tid = threadIdx.x;
    const int tx = tid & 15, ty = tid >> 4;
    const int eb = blockIdx.x * 128;
    const int nb = blockIdx.y * 128;

    float acc[8][8];
    #pragma unroll
    for (int i = 0; i < 8; ++i)
        #pragma unroll
        for (int j = 0; j < 8; ++j) acc[i][j] = 0.0f;

    for (int kb = 0; kb < 1024; kb += 16) {
        #pragma unroll
        for (int l = 0; l < 2; ++l) {
            int fid = tid + l * 256;
            int r = fid >> 2, c4 = (fid & 3) * 4;
            size_t aoff = (size_t)(nb + r) * 1024 + kb + c4;
            float4 a1 = *(const float4*)(c1 + aoff);
            float4 a2 = *(const float4*)(c2 + aoff);
            sA[c4+0][r] = a1.x + a2.x; sA[c4+1][r] = a1.y + a2.y;
            sA[c4+2][r] = a1.z + a2.z; sA[c4+3][r] = a1.w + a2.w;
            float4 wv = *(const float4*)(Wo + (size_t)(eb + r) * 1024 + kb + c4);
            sB[c4+0][r] = wv.x; sB[c4+1][r] = wv.y; sB[c4+2][r] = wv.z; sB[c4+3][r] = wv.w;
        }
        __syncthreads();
        #pragma unroll
        for (int kk = 0; kk < 16; ++kk) {
            float a[8], b[8];
            *(float4*)&a[0] = *(const float4*)&sA[kk][ty*8];
            *(float4*)&a[4] = *(const float4*)&sA[kk][ty*8+4];
            *(float4*)&b[0] = *(const float4*)&sB[kk][tx*8];
            *(float4*)&b[4] = *(const float4*)&sB[kk][tx*8+4];
            #pragma unroll
            for (int i = 0; i < 8; ++i)
                #pragma unroll
                for (int j = 0; j < 8; ++j) acc[i][j] += a[i] * b[j];
        }
        __syncthreads();
    }
    float bb[8];
    *(float4*)&bb[0] = *(const float4*)(bo + eb + tx*8);
    *(float4*)&bb[4] = *(const float4*)(bo + eb + tx*8 + 4);
    #pragma unroll
    for (int i = 0; i < 8; ++i) {
        int n = nb + ty*8 + i;
        #pragma unroll
        for (int jj = 0; jj < 2; ++jj) {
            float4 o;
            o.x = acc[i][jj*4+0] + bb[jj*4+0];
            o.y = acc[i][jj*4+1] + bb[jj*4+1];
            o.z = acc[i][jj*4+2] + bb[jj*4+2];
            o.w = acc[i][jj*4+3] + bb[jj*4+3];
            *(float4*)(outp + (size_t)n * 1024 + eb + tx*8 + jj*4) = o;
        }
    }
}

// ---------------------------------------------------------------------------
extern "C" void kernel_launch(void* const* d_in, const int* in_sizes, int n_in,
                              void* d_out, int out_size, void* d_ws, size_t ws_size,
                              hipStream_t stream) {
    const float* hs   = (const float*)d_in[0];
    const float* Wq   = (const float*)d_in[1];
    const float* bq   = (const float*)d_in[2];
    const float* Wk   = (const float*)d_in[3];
    const float* bk   = (const float*)d_in[4];
    const float* Wv   = (const float*)d_in[5];
    const float* bv   = (const float*)d_in[6];
    const float* Wo   = (const float*)d_in[7];
    const float* bo   = (const float*)d_in[8];
    const float* relk = (const float*)d_in[9];
    const float* relv = (const float*)d_in[10];
    float* out = (float*)d_out;

    // Workspace: 5 x 4,194,304 floats = 80 MB.
    float* ws = (float*)d_ws;
    float* qs = ws;
    float* ks = ws + 4194304;
    float* vs = ws + 8388608;
    float* c1 = ws + 12582912;
    float* c2 = ws + 16777216;

    k_qkv  <<<dim3(8, 32, 3), 256, 0, stream>>>(hs, Wq, bq, Wk, bk, Wv, bv, qs, ks, vs);
    k_fused<<<dim3(64, 64),   256, 0, stream>>>(qs, ks, vs, relk, relv, c1, c2);
    k_oproj<<<dim3(8, 32),    256, 0, stream>>>(c1, c2, Wo, bo, out);
}

// Round 5
// 1585.655 us; speedup vs baseline: 8.4512x; 7.5665x over previous
//
#include <hip/hip_runtime.h>
#include <hip/hip_bf16.h>

// B=4, T=1024, E=1024, H=16, D=64, P=257.  Slot s = b*16+h (64 slots).
// Torch view(B*H)->(H,B) quirk: score slot m reads rel-K table of slot
// pm=(m&15)*4+(m>>4); attn of slot m feeds the w2 output of slot
// m2=(m&3)*16+(m>>2)  (pm(m2)==m).
// Workspace: qs/ks/vs/c1/c2 = 5 x 4M floats = 80 MB total.
//
// k_fused is flash-style online softmax. w2 accumulated online via
// w2[q] += e * relv[clip(q-k)+128] (same alpha-rescale as w1); no score row
// or banded-A matrix materialized; max 4 resident scores/thread (no spill).
// R4 bug: K/V staging covered only 16 of 64 rows -> uninit LDS -> NaN.
// R5 fix: 4-iteration staging loops (1024 float4 = 64 rows).

// ---------------------------------------------------------------------------
// K1: fused QKV projection.  q/k/v[n,e] = hs[n,:]·W[e,:] + b[e]; q scaled 1/8.
// Output in slot layout: out[((b*16+h)*1024 + t)*64 + d].
// ---------------------------------------------------------------------------
__global__ __launch_bounds__(256) void k_qkv(
    const float* __restrict__ hs,
    const float* __restrict__ Wq, const float* __restrict__ bq,
    const float* __restrict__ Wk, const float* __restrict__ bk,
    const float* __restrict__ Wv, const float* __restrict__ bv,
    float* __restrict__ qs, float* __restrict__ ks, float* __restrict__ vs)
{
    __shared__ float sA[16][132];
    __shared__ float sB[16][132];
    const int tid = threadIdx.x;
    const int tx = tid & 15, ty = tid >> 4;
    const int eb = blockIdx.x * 128;
    const int nb = blockIdx.y * 128;
    const int z = blockIdx.z;
    const float* W    = (z == 0) ? Wq : (z == 1) ? Wk : Wv;
    const float* bias = (z == 0) ? bq : (z == 1) ? bk : bv;
    float* out        = (z == 0) ? qs : (z == 1) ? ks : vs;
    const float scale = (z == 0) ? 0.125f : 1.0f;

    float acc[8][8];
    #pragma unroll
    for (int i = 0; i < 8; ++i)
        #pragma unroll
        for (int j = 0; j < 8; ++j) acc[i][j] = 0.0f;

    for (int kb = 0; kb < 1024; kb += 16) {
        #pragma unroll
        for (int l = 0; l < 2; ++l) {
            int fid = tid + l * 256;
            int r = fid >> 2, c4 = (fid & 3) * 4;
            float4 av = *(const float4*)(hs + (size_t)(nb + r) * 1024 + kb + c4);
            sA[c4+0][r] = av.x; sA[c4+1][r] = av.y; sA[c4+2][r] = av.z; sA[c4+3][r] = av.w;
            float4 wv = *(const float4*)(W + (size_t)(eb + r) * 1024 + kb + c4);
            sB[c4+0][r] = wv.x; sB[c4+1][r] = wv.y; sB[c4+2][r] = wv.z; sB[c4+3][r] = wv.w;
        }
        __syncthreads();
        #pragma unroll
        for (int kk = 0; kk < 16; ++kk) {
            float a[8], b[8];
            *(float4*)&a[0] = *(const float4*)&sA[kk][ty*8];
            *(float4*)&a[4] = *(const float4*)&sA[kk][ty*8+4];
            *(float4*)&b[0] = *(const float4*)&sB[kk][tx*8];
            *(float4*)&b[4] = *(const float4*)&sB[kk][tx*8+4];
            #pragma unroll
            for (int i = 0; i < 8; ++i)
                #pragma unroll
                for (int j = 0; j < 8; ++j) acc[i][j] += a[i] * b[j];
        }
        __syncthreads();
    }
    float bb[8];
    *(float4*)&bb[0] = *(const float4*)(bias + eb + tx*8);
    *(float4*)&bb[4] = *(const float4*)(bias + eb + tx*8 + 4);
    #pragma unroll
    for (int i = 0; i < 8; ++i) {
        int n = nb + ty*8 + i;
        int bidx = n >> 10, t = n & 1023;
        #pragma unroll
        for (int jj = 0; jj < 2; ++jj) {
            int e0 = eb + tx*8 + jj*4;
            int h = e0 >> 6, d = e0 & 63;
            float4 o;
            o.x = (acc[i][jj*4+0] + bb[jj*4+0]) * scale;
            o.y = (acc[i][jj*4+1] + bb[jj*4+1]) * scale;
            o.z = (acc[i][jj*4+2] + bb[jj*4+2]) * scale;
            o.w = (acc[i][jj*4+3] + bb[jj*4+3]) * scale;
            *(float4*)(out + (size_t)((bidx*16 + h) * 1024 + t) * 64 + d) = o;
        }
    }
}

// ---------------------------------------------------------------------------
// K2: flash-style fused attention.  Block = (slot m, 16 q-rows).
// Thread (qt,l): qt=tid>>4 owns q-row q0+qt; l=tid&15 owns k-cols l+16*kk and
// d-dims l*4..l*4+3.  Q row lives in 64 VGPRs.  Online softmax state (mrow,
// lrow) redundant across the 16 lanes of a row; reductions via 16-lane shfl.
// ---------------------------------------------------------------------------
__global__ __launch_bounds__(256) void k_fused(
    const float* __restrict__ qs, const float* __restrict__ ks,
    const float* __restrict__ vs, const float* __restrict__ relk,
    const float* __restrict__ relv,
    float* __restrict__ c1, float* __restrict__ c2)
{
    __shared__ float sR[16][257];    // 16448 B  rel-K score bias per q-row
    __shared__ float sKV[64][68];    // 17408 B  K tile, then V tile
    __shared__ float sRelW[80][68];  // 21760 B  relv window rows lo..hi
    __shared__ float sP[16][68];     //  4352 B  exp(scores) tile -> 59968 B
    const int tid = threadIdx.x;
    const int m = blockIdx.y;
    const int q0 = blockIdx.x * 16;
    const int pm = (m & 15) * 4 + (m >> 4);
    const int m2 = (m & 3) * 16 + (m >> 2);
    const int qt = tid >> 4;
    const int l  = tid & 15;
    const int qg = q0 + qt;
    const int dw = l * 4;

    // ---- Phase A: R slice sR[q][j] = Q[pm][q]·relk[j] ----
    float4 qv[16];
    {
        const float* qpm = qs + (size_t)(pm*1024 + qg) * 64;
        #pragma unroll
        for (int d4 = 0; d4 < 16; ++d4) qv[d4] = *(const float4*)(qpm + d4*4);
    }
    #pragma unroll 1
    for (int jj = 0; jj < 17; ++jj) {
        int j = jj*16 + l;
        if (j < 257) {
            const float* rk = relk + j*64;
            float a = 0.0f;
            #pragma unroll
            for (int d4 = 0; d4 < 16; ++d4) {
                float4 rv = *(const float4*)(rk + d4*4);
                a += qv[d4].x*rv.x + qv[d4].y*rv.y + qv[d4].z*rv.z + qv[d4].w*rv.w;
            }
            sR[qt][j] = a;
        }
    }
    {
        const float* qm = qs + (size_t)(m*1024 + qg) * 64;
        #pragma unroll
        for (int d4 = 0; d4 < 16; ++d4) qv[d4] = *(const float4*)(qm + d4*4);
    }
    __syncthreads();

    // ---- Main loop over 16 k-tiles of 64 ----
    float mrow = -1e30f, lrow = 0.0f;
    float4 o1 = make_float4(0,0,0,0), o2 = make_float4(0,0,0,0);

    #pragma unroll 1
    for (int kt = 0; kt < 16; ++kt) {
        const int k0 = kt * 64;
        // stage K tile: 64 rows x 16 float4 = 1024 float4, 4 per thread
        #pragma unroll
        for (int lq = 0; lq < 4; ++lq) {
            int f = tid + lq * 256;
            int r = f >> 4, c4 = (f & 15) * 4;
            *(float4*)&sKV[r][c4] = *(const float4*)(ks + (size_t)(m*1024 + k0 + r) * 64 + c4);
        }
        // stage relv window rows lo..hi (dist range of this (q0,k0) tile)
        const int lo = min(256, max(0, q0 - k0 - 63 + 128));
        const int hi = min(256, max(0, q0 - k0 + 15 + 128));
        const int nr = hi - lo + 1;
        #pragma unroll 1
        for (int idx = tid; idx < nr * 16; idx += 256) {
            int r = idx >> 4, c4 = (idx & 15) * 4;
            *(float4*)&sRelW[r][c4] = *(const float4*)(relv + (size_t)(lo + r) * 64 + c4);
        }
        __syncthreads();

        // scores for k = k0 + kk*16 + l, kk in [0,4)
        float sc[4];
        #pragma unroll
        for (int kk = 0; kk < 4; ++kk) {
            int k = kk*16 + l;
            float a = 0.0f;
            #pragma unroll
            for (int d4 = 0; d4 < 16; ++d4) {
                float4 k4 = *(const float4*)&sKV[k][d4*4];
                a += qv[d4].x*k4.x + qv[d4].y*k4.y + qv[d4].z*k4.z + qv[d4].w*k4.w;
            }
            int dist = qg - (k0 + k);
            int jd = dist < -128 ? 0 : (dist > 128 ? 256 : dist + 128);
            sc[kk] = a + sR[qt][jd];
        }
        // online softmax update (16-lane row groups)
        float mloc = fmaxf(fmaxf(sc[0], sc[1]), fmaxf(sc[2], sc[3]));
        #pragma unroll
        for (int off = 1; off < 16; off <<= 1) mloc = fmaxf(mloc, __shfl_xor(mloc, off, 64));
        float mnew = fmaxf(mrow, mloc);
        float alpha = exp2f((mrow - mnew) * 1.44269504f);
        float esum = 0.0f;
        #pragma unroll
        for (int kk = 0; kk < 4; ++kk) {
            float e = exp2f((sc[kk] - mnew) * 1.44269504f);
            sP[qt][kk*16 + l] = e;
            esum += e;
        }
        #pragma unroll
        for (int off = 1; off < 16; off <<= 1) esum += __shfl_xor(esum, off, 64);
        lrow = lrow * alpha + esum;
        mrow = mnew;
        o1.x *= alpha; o1.y *= alpha; o1.z *= alpha; o1.w *= alpha;
        o2.x *= alpha; o2.y *= alpha; o2.z *= alpha; o2.w *= alpha;
        __syncthreads();   // sP ready; done reading K from sKV

        // stage V tile into same buffer (64 rows, 4 float4 per thread)
        #pragma unroll
        for (int lq = 0; lq < 4; ++lq) {
            int f = tid + lq * 256;
            int r = f >> 4, c4 = (f & 15) * 4;
            *(float4*)&sKV[r][c4] = *(const float4*)(vs + (size_t)(m*1024 + k0 + r) * 64 + c4);
        }
        __syncthreads();

        // accumulate o1 += P·V, o2 += P·relv[window]
        #pragma unroll 4
        for (int kk = 0; kk < 64; ++kk) {
            float p = sP[qt][kk];
            float4 v4 = *(const float4*)&sKV[kk][dw];
            o1.x += p*v4.x; o1.y += p*v4.y; o1.z += p*v4.z; o1.w += p*v4.w;
            int idxr = qg - (k0 + kk) + 128;
            idxr = idxr < lo ? lo : (idxr > hi ? hi : idxr);
            float4 r4 = *(const float4*)&sRelW[idxr - lo][dw];
            o2.x += p*r4.x; o2.y += p*r4.y; o2.z += p*r4.z; o2.w += p*r4.w;
        }
        __syncthreads();   // done reading V/relW before next tile overwrites
    }

    const float inv = 1.0f / lrow;
    const int b1 = m >> 4,  h1 = m & 15;
    const int b2 = m2 >> 4, h2 = m2 & 15;
    *(float4*)(c1 + (size_t)(b1*1024 + qg) * 1024 + h1*64 + dw) =
        make_float4(o1.x*inv, o1.y*inv, o1.z*inv, o1.w*inv);
    *(float4*)(c2 + (size_t)(b2*1024 + qg) * 1024 + h2*64 + dw) =
        make_float4(o2.x*inv, o2.y*inv, o2.z*inv, o2.w*inv);
}

// ---------------------------------------------------------------------------
// K3: out = (c1+c2) @ Wo^T + bo   (4096x1024x1024)
// ---------------------------------------------------------------------------
__global__ __launch_bounds__(256) void k_oproj(
    const float* __restrict__ c1, const float* __restrict__ c2,
    const float* __restrict__ Wo, const float* __restrict__ bo,
    float* __restrict__ outp)
{
    __shared__ float sA[16][132];
    __shared__ float sB[16][132];
    const int tid = threadIdx.x;
    const int tx = tid & 15, ty = tid >> 4;
    const int eb = blockIdx.x * 128;
    const int nb = blockIdx.y * 128;

    float acc[8][8];
    #pragma unroll
    for (int i = 0; i < 8; ++i)
        #pragma unroll
        for (int j = 0; j < 8; ++j) acc[i][j] = 0.0f;

    for (int kb = 0; kb < 1024; kb += 16) {
        #pragma unroll
        for (int l = 0; l < 2; ++l) {
            int fid = tid + l * 256;
            int r = fid >> 2, c4 = (fid & 3) * 4;
            size_t aoff = (size_t)(nb + r) * 1024 + kb + c4;
            float4 a1 = *(const float4*)(c1 + aoff);
            float4 a2 = *(const float4*)(c2 + aoff);
            sA[c4+0][r] = a1.x + a2.x; sA[c4+1][r] = a1.y + a2.y;
            sA[c4+2][r] = a1.z + a2.z; sA[c4+3][r] = a1.w + a2.w;
            float4 wv = *(const float4*)(Wo + (size_t)(eb + r) * 1024 + kb + c4);
            sB[c4+0][r] = wv.x; sB[c4+1][r] = wv.y; sB[c4+2][r] = wv.z; sB[c4+3][r] = wv.w;
        }
        __syncthreads();
        #pragma unroll
        for (int kk = 0; kk < 16; ++kk) {
            float a[8], b[8];
            *(float4*)&a[0] = *(const float4*)&sA[kk][ty*8];
            *(float4*)&a[4] = *(const float4*)&sA[kk][ty*8+4];
            *(float4*)&b[0] = *(const float4*)&sB[kk][tx*8];
            *(float4*)&b[4] = *(const float4*)&sB[kk][tx*8+4];
            #pragma unroll
            for (int i = 0; i < 8; ++i)
                #pragma unroll
                for (int j = 0; j < 8; ++j) acc[i][j] += a[i] * b[j];
        }
        __syncthreads();
    }
    float bb[8];
    *(float4*)&bb[0] = *(const float4*)(bo + eb + tx*8);
    *(float4*)&bb[4] = *(const float4*)(bo + eb + tx*8 + 4);
    #pragma unroll
    for (int i = 0; i < 8; ++i) {
        int n = nb + ty*8 + i;
        #pragma unroll
        for (int jj = 0; jj < 2; ++jj) {
            float4 o;
            o.x = acc[i][jj*4+0] + bb[jj*4+0];
            o.y = acc[i][jj*4+1] + bb[jj*4+1];
            o.z = acc[i][jj*4+2] + bb[jj*4+2];
            o.w = acc[i][jj*4+3] + bb[jj*4+3];
            *(float4*)(outp + (size_t)n * 1024 + eb + tx*8 + jj*4) = o;
        }
    }
}

// ---------------------------------------------------------------------------
extern "C" void kernel_launch(void* const* d_in, const int* in_sizes, int n_in,
                              void* d_out, int out_size, void* d_ws, size_t ws_size,
                              hipStream_t stream) {
    const float* hs   = (const float*)d_in[0];
    const float* Wq   = (const float*)d_in[1];
    const float* bq   = (const float*)d_in[2];
    const float* Wk   = (const float*)d_in[3];
    const float* bk   = (const float*)d_in[4];
    const float* Wv   = (const float*)d_in[5];
    const float* bv   = (const float*)d_in[6];
    const float* Wo   = (const float*)d_in[7];
    const float* bo   = (const float*)d_in[8];
    const float* relk = (const float*)d_in[9];
    const float* relv = (const float*)d_in[10];
    float* out = (float*)d_out;

    // Workspace: 5 x 4,194,304 floats = 80 MB.
    float* ws = (float*)d_ws;
    float* qs = ws;
    float* ks = ws + 4194304;
    float* vs = ws + 8388608;
    float* c1 = ws + 12582912;
    float* c2 = ws + 16777216;

    k_qkv  <<<dim3(8, 32, 3), 256, 0, stream>>>(hs, Wq, bq, Wk, bk, Wv, bv, qs, ks, vs);
    k_fused<<<dim3(64, 64),   256, 0, stream>>>(qs, ks, vs, relk, relv, c1, c2);
    k_oproj<<<dim3(8, 32),    256, 0, stream>>>(c1, c2, Wo, bo, out);
}

// Round 6
// 1193.116 us; speedup vs baseline: 11.2317x; 1.3290x over previous
//
#include <hip/hip_runtime.h>
#include <hip/hip_bf16.h>

// B=4, T=1024, E=1024, H=16, D=64, P=257.  Slot s = b*16+h (64 slots).
// Quirk: score slot m uses rel-K of slot pm=(m&15)*4+(m>>4); attn of slot m
// feeds w2 output of slot m2=(m&3)*16+(m>>2).
// k_fused (R6): MFMA flash attention. QK^T and P·V via mfma_f32_16x16x32_bf16.
// w2 online: fully-clipped k-tiles (|dist|>=128) contribute rowsum(e)*relv[edge]
// (rowsum = softmax partial, free); interior tiles via gathered-G MFMA against
// an LDS relv window; partial tiles via small serial scatter.

typedef __attribute__((ext_vector_type(8))) short short8;
typedef __attribute__((ext_vector_type(4))) float f32x4;

__device__ __forceinline__ float bf16f(unsigned int u) {
    union { unsigned int i; float f; } v; v.i = u << 16; return v.f;
}
__device__ __forceinline__ unsigned short f2b(float x) {
    __hip_bfloat16 h = __float2bfloat16(x);
    return *reinterpret_cast<unsigned short*>(&h);
}
__device__ __forceinline__ unsigned int pack2(float a, float b) {
    return (unsigned int)f2b(a) | ((unsigned int)f2b(b) << 16);
}

// ---------------------------------------------------------------------------
// K1: fused QKV projection (fp32, 96 TF measured).  q scaled 1/8.
// ---------------------------------------------------------------------------
__global__ __launch_bounds__(256) void k_qkv(
    const float* __restrict__ hs,
    const float* __restrict__ Wq, const float* __restrict__ bq,
    const float* __restrict__ Wk, const float* __restrict__ bk,
    const float* __restrict__ Wv, const float* __restrict__ bv,
    float* __restrict__ qs, float* __restrict__ ks, float* __restrict__ vs)
{
    __shared__ float sA[16][132];
    __shared__ float sB[16][132];
    const int tid = threadIdx.x;
    const int tx = tid & 15, ty = tid >> 4;
    const int eb = blockIdx.x * 128;
    const int nb = blockIdx.y * 128;
    const int z = blockIdx.z;
    const float* W    = (z == 0) ? Wq : (z == 1) ? Wk : Wv;
    const float* bias = (z == 0) ? bq : (z == 1) ? bk : bv;
    float* out        = (z == 0) ? qs : (z == 1) ? ks : vs;
    const float scale = (z == 0) ? 0.125f : 1.0f;

    float acc[8][8];
    #pragma unroll
    for (int i = 0; i < 8; ++i)
        #pragma unroll
        for (int j = 0; j < 8; ++j) acc[i][j] = 0.0f;

    for (int kb = 0; kb < 1024; kb += 16) {
        #pragma unroll
        for (int l = 0; l < 2; ++l) {
            int fid = tid + l * 256;
            int r = fid >> 2, c4 = (fid & 3) * 4;
            float4 av = *(const float4*)(hs + (size_t)(nb + r) * 1024 + kb + c4);
            sA[c4+0][r] = av.x; sA[c4+1][r] = av.y; sA[c4+2][r] = av.z; sA[c4+3][r] = av.w;
            float4 wv = *(const float4*)(W + (size_t)(eb + r) * 1024 + kb + c4);
            sB[c4+0][r] = wv.x; sB[c4+1][r] = wv.y; sB[c4+2][r] = wv.z; sB[c4+3][r] = wv.w;
        }
        __syncthreads();
        #pragma unroll
        for (int kk = 0; kk < 16; ++kk) {
            float a[8], b[8];
            *(float4*)&a[0] = *(const float4*)&sA[kk][ty*8];
            *(float4*)&a[4] = *(const float4*)&sA[kk][ty*8+4];
            *(float4*)&b[0] = *(const float4*)&sB[kk][tx*8];
            *(float4*)&b[4] = *(const float4*)&sB[kk][tx*8+4];
            #pragma unroll
            for (int i = 0; i < 8; ++i)
                #pragma unroll
                for (int j = 0; j < 8; ++j) acc[i][j] += a[i] * b[j];
        }
        __syncthreads();
    }
    float bb[8];
    *(float4*)&bb[0] = *(const float4*)(bias + eb + tx*8);
    *(float4*)&bb[4] = *(const float4*)(bias + eb + tx*8 + 4);
    #pragma unroll
    for (int i = 0; i < 8; ++i) {
        int n = nb + ty*8 + i;
        int bidx = n >> 10, t = n & 1023;
        #pragma unroll
        for (int jj = 0; jj < 2; ++jj) {
            int e0 = eb + tx*8 + jj*4;
            int h = e0 >> 6, d = e0 & 63;
            float4 o;
            o.x = (acc[i][jj*4+0] + bb[jj*4+0]) * scale;
            o.y = (acc[i][jj*4+1] + bb[jj*4+1]) * scale;
            o.z = (acc[i][jj*4+2] + bb[jj*4+2]) * scale;
            o.w = (acc[i][jj*4+3] + bb[jj*4+3]) * scale;
            *(float4*)(out + (size_t)((bidx*16 + h) * 1024 + t) * 64 + d) = o;
        }
    }
}

// ---------------------------------------------------------------------------
// K2: MFMA flash attention.  Block = (slot m, 16 q-rows), 4 waves.
// Wave w owns col-tile w (16 cols) of every 16-wide MFMA output.
// ---------------------------------------------------------------------------
__global__ __launch_bounds__(256) void k_fused(
    const float* __restrict__ qs, const float* __restrict__ ks,
    const float* __restrict__ vs, const float* __restrict__ relk,
    const float* __restrict__ relv,
    float* __restrict__ c1, float* __restrict__ c2)
{
    __shared__ __align__(16) unsigned short sQ[16][72];    //  2304 B  Q bf16 row-major
    __shared__ __align__(16) unsigned short sK[64][72];    //  9216 B  K [kcol][dim]
    __shared__ __align__(16) unsigned short sVT[64][72];   //  9216 B  V^T [d][k]
    __shared__ __align__(16) unsigned short sP[16][72];    //  2304 B  P bf16 [q][k]
    __shared__ __align__(16) unsigned short sG[16][104];   //  3328 B  gathered P [q][jwin]
    __shared__ __align__(16) unsigned short sRWT[64][104]; // 13312 B  relW^T [d][jwin]
    __shared__ __align__(16) unsigned short sR[16][264];   //  8448 B  rel-K bias bf16
    __shared__ float sPartMax[4][16];                      //   256 B
    __shared__ float sPartSum[4][16];                      //   256 B
    __shared__ float sRelEdge[2][64];                      //   512 B  => 49152 B

    const int tid = threadIdx.x;
    const int m  = blockIdx.y;
    const int q0 = blockIdx.x * 16;
    const int pm = (m & 15) * 4 + (m >> 4);
    const int m2 = (m & 3) * 16 + (m >> 2);
    const int w    = tid >> 6;
    const int lane = tid & 63;
    const int lq   = lane & 15;
    const int quad = lane >> 4;

    // ---- Phase A: stage Q (bf16), rel edges, compute R bias (fp32->bf16) ----
    {
        int r = tid >> 4, c4 = (tid & 15) * 4;
        float4 q4 = *(const float4*)(qs + (size_t)(m*1024 + q0 + r) * 64 + c4);
        *(unsigned int*)&sQ[r][c4]   = pack2(q4.x, q4.y);
        *(unsigned int*)&sQ[r][c4+2] = pack2(q4.z, q4.w);
    }
    if (tid < 128) {
        int e = tid >> 6, d = tid & 63;
        sRelEdge[e][d] = relv[(size_t)(e * 256) * 64 + d];
    }
    {
        const int qt = tid >> 4, l = tid & 15;
        float4 qv[16];
        const float* qpm = qs + (size_t)(pm*1024 + q0 + qt) * 64;
        #pragma unroll
        for (int d4 = 0; d4 < 16; ++d4) qv[d4] = *(const float4*)(qpm + d4*4);
        #pragma unroll 1
        for (int jj = 0; jj < 17; ++jj) {
            int j = jj*16 + l;
            if (j < 257) {
                const float* rk = relk + j*64;
                float a = 0.0f;
                #pragma unroll
                for (int d4 = 0; d4 < 16; ++d4) {
                    float4 rv = *(const float4*)(rk + d4*4);
                    a += qv[d4].x*rv.x + qv[d4].y*rv.y + qv[d4].z*rv.z + qv[d4].w*rv.w;
                }
                sR[qt][j] = f2b(a);
            }
        }
    }
    __syncthreads();

    // Q A-fragments are loop-invariant: hoist.
    short8 aq0 = *(const short8*)&sQ[lq][quad*8];
    short8 aq1 = *(const short8*)&sQ[lq][32 + quad*8];
    const float relE0 = sRelEdge[0][w*16 + lq];
    const float relE1 = sRelEdge[1][w*16 + lq];

    float mrow[4], lrow[4];
    f32x4 c1a = {0,0,0,0}, c2a = {0,0,0,0};
    #pragma unroll
    for (int i = 0; i < 4; ++i) { mrow[i] = -1e30f; lrow[i] = 0.0f; }

    #pragma unroll 1
    for (int kt = 0; kt < 16; ++kt) {
        const int k0 = kt * 64;
        const int jminU = q0 - k0 - 63 + 128;
        const int jmaxU = q0 + 15 - k0 + 128;
        const bool fully_low  = (jmaxU <= 0);
        const bool fully_high = (jminU >= 256);
        const bool fully_clipped = fully_low || fully_high;
        const bool needG = !fully_clipped;
        const int jlo = jminU < 0 ? 0 : jminU;
        const int jhi = jmaxU > 256 ? 256 : jmaxU;
        const int width = jhi - jlo + 1;
        const bool pure_interior = (jminU >= 0) && (jmaxU <= 256);

        // ---- stage K, V^T ----
        #pragma unroll
        for (int i = 0; i < 4; ++i) {
            int f = tid + i * 256;
            int r = f >> 4, c4 = (f & 15) * 4;
            float4 k4 = *(const float4*)(ks + (size_t)(m*1024 + k0 + r) * 64 + c4);
            *(unsigned int*)&sK[r][c4]   = pack2(k4.x, k4.y);
            *(unsigned int*)&sK[r][c4+2] = pack2(k4.z, k4.w);
            float4 v4 = *(const float4*)(vs + (size_t)(m*1024 + k0 + r) * 64 + c4);
            sVT[c4+0][r] = f2b(v4.x); sVT[c4+1][r] = f2b(v4.y);
            sVT[c4+2][r] = f2b(v4.z); sVT[c4+3][r] = f2b(v4.w);
        }
        if (needG) {
            // stage relW^T window (zero-fill beyond width) and zero G
            #pragma unroll
            for (int i = 0; i < 6; ++i) {
                int f = tid + i * 256;
                int jw = f >> 4, c4 = (f & 15) * 4;
                if (jw < width) {
                    float4 rv = *(const float4*)(relv + (size_t)(jlo + jw) * 64 + c4);
                    sRWT[c4+0][jw] = f2b(rv.x); sRWT[c4+1][jw] = f2b(rv.y);
                    sRWT[c4+2][jw] = f2b(rv.z); sRWT[c4+3][jw] = f2b(rv.w);
                } else {
                    sRWT[c4+0][jw] = 0; sRWT[c4+1][jw] = 0;
                    sRWT[c4+2][jw] = 0; sRWT[c4+3][jw] = 0;
                }
            }
            for (int i = tid; i < 832; i += 256) ((unsigned int*)sG)[i] = 0u;
        }
        __syncthreads();   // B1: tiles staged

        // ---- QK^T MFMA (wave w: cols k0+w*16 .. +15) ----
        short8 bk0 = *(const short8*)&sK[w*16 + lq][quad*8];
        short8 bk1 = *(const short8*)&sK[w*16 + lq][32 + quad*8];
        f32x4 s4 = {0,0,0,0};
        s4 = __builtin_amdgcn_mfma_f32_16x16x32_bf16(aq0, bk0, s4, 0, 0, 0);
        s4 = __builtin_amdgcn_mfma_f32_16x16x32_bf16(aq1, bk1, s4, 0, 0, 0);

        float sc[4], mloc[4];
        const int kcol = k0 + w*16 + lq;
        #pragma unroll
        for (int i = 0; i < 4; ++i) {
            int row = quad*4 + i;
            int dist = (q0 + row) - kcol;
            int jd = dist < -128 ? 0 : (dist > 128 ? 256 : dist + 128);
            sc[i] = s4[i] + bf16f(sR[row][jd]);
            mloc[i] = sc[i];
        }
        #pragma unroll
        for (int off = 1; off < 16; off <<= 1)
            #pragma unroll
            for (int i = 0; i < 4; ++i)
                mloc[i] = fmaxf(mloc[i], __shfl_xor(mloc[i], off, 64));
        if (lq == 0) {
            #pragma unroll
            for (int i = 0; i < 4; ++i) sPartMax[w][quad*4 + i] = mloc[i];
        }
        __syncthreads();   // B2: partial maxima

        float mnew[4], alpha[4], e[4], psum[4];
        #pragma unroll
        for (int i = 0; i < 4; ++i) {
            int row = quad*4 + i;
            float ma = fmaxf(fmaxf(sPartMax[0][row], sPartMax[1][row]),
                             fmaxf(sPartMax[2][row], sPartMax[3][row]));
            mnew[i] = fmaxf(mrow[i], ma);
            alpha[i] = exp2f((mrow[i] - mnew[i]) * 1.44269504f);
            e[i] = exp2f((sc[i] - mnew[i]) * 1.44269504f);
            psum[i] = e[i];
        }
        #pragma unroll
        for (int off = 1; off < 16; off <<= 1)
            #pragma unroll
            for (int i = 0; i < 4; ++i)
                psum[i] += __shfl_xor(psum[i], off, 64);
        if (lq == 0) {
            #pragma unroll
            for (int i = 0; i < 4; ++i) sPartSum[w][quad*4 + i] = psum[i];
        }
        #pragma unroll
        for (int i = 0; i < 4; ++i) sP[quad*4 + i][w*16 + lq] = f2b(e[i]);
        __syncthreads();   // B3: P + partial sums ready

        float sAll[4];
        #pragma unroll
        for (int i = 0; i < 4; ++i) {
            int row = quad*4 + i;
            sAll[i] = sPartSum[0][row] + sPartSum[1][row]
                    + sPartSum[2][row] + sPartSum[3][row];
            lrow[i] = lrow[i] * alpha[i] + sAll[i];
            mrow[i] = mnew[i];
            c1a[i] *= alpha[i];
            c2a[i] *= alpha[i];
        }

        // ---- P·V MFMA ----
        {
            short8 ap0 = *(const short8*)&sP[lq][quad*8];
            short8 ap1 = *(const short8*)&sP[lq][32 + quad*8];
            short8 bv0 = *(const short8*)&sVT[w*16 + lq][quad*8];
            short8 bv1 = *(const short8*)&sVT[w*16 + lq][32 + quad*8];
            c1a = __builtin_amdgcn_mfma_f32_16x16x32_bf16(ap0, bv0, c1a, 0, 0, 0);
            c1a = __builtin_amdgcn_mfma_f32_16x16x32_bf16(ap1, bv1, c1a, 0, 0, 0);
        }

        // ---- rel-V contribution ----
        if (fully_clipped) {
            float re = fully_low ? relE0 : relE1;
            #pragma unroll
            for (int i = 0; i < 4; ++i) c2a[i] += sAll[i] * re;
        } else {
            if (pure_interior) {
                #pragma unroll
                for (int i2 = 0; i2 < 4; ++i2) {
                    int idx = tid + i2 * 256;
                    int q = idx >> 6, k2 = idx & 63;
                    int jd = (q0 + q) - (k0 + k2) + 128;
                    sG[q][jd - jlo] = sP[q][k2];
                }
            } else if (tid < 64) {
                int q = tid >> 2, part = tid & 3;
                float e0 = 0.0f, e256 = 0.0f;
                #pragma unroll 1
                for (int kk = part*16; kk < part*16 + 16; ++kk) {
                    int dist = (q0 + q) - (k0 + kk);
                    if (dist <= -128)      e0   += bf16f(sP[q][kk]);
                    else if (dist >= 128)  e256 += bf16f(sP[q][kk]);
                    else                   sG[q][dist + 128 - jlo] = sP[q][kk];
                }
                e0   += __shfl_xor(e0, 1, 64);   e0   += __shfl_xor(e0, 2, 64);
                e256 += __shfl_xor(e256, 1, 64); e256 += __shfl_xor(e256, 2, 64);
                if (part == 0) {
                    if (jlo == 0)  sG[q][0]         = f2b(e0);
                    if (jhi == 256) sG[q][256 - jlo] = f2b(e256);
                }
            }
            __syncthreads();   // B4: G built (needG is block-uniform)
            short8 ag0 = *(const short8*)&sG[lq][quad*8];
            short8 ag1 = *(const short8*)&sG[lq][32 + quad*8];
            short8 ag2 = *(const short8*)&sG[lq][64 + quad*8];
            short8 br0 = *(const short8*)&sRWT[w*16 + lq][quad*8];
            short8 br1 = *(const short8*)&sRWT[w*16 + lq][32 + quad*8];
            short8 br2 = *(const short8*)&sRWT[w*16 + lq][64 + quad*8];
            c2a = __builtin_amdgcn_mfma_f32_16x16x32_bf16(ag0, br0, c2a, 0, 0, 0);
            c2a = __builtin_amdgcn_mfma_f32_16x16x32_bf16(ag1, br1, c2a, 0, 0, 0);
            c2a = __builtin_amdgcn_mfma_f32_16x16x32_bf16(ag2, br2, c2a, 0, 0, 0);
        }
        __syncthreads();   // B5: end of tile (before restage)
    }

    // ---- epilogue: normalize + store (C layout: row=quad*4+i, col=w*16+lq) ----
    const int b1 = m >> 4,  h1 = m & 15;
    const int b2 = m2 >> 4, h2 = m2 & 15;
    #pragma unroll
    for (int i = 0; i < 4; ++i) {
        int row = quad*4 + i;
        float inv = 1.0f / lrow[i];
        size_t col = w*16 + lq;
        c1[(size_t)(b1*1024 + q0 + row) * 1024 + h1*64 + col] = c1a[i] * inv;
        c2[(size_t)(b2*1024 + q0 + row) * 1024 + h2*64 + col] = c2a[i] * inv;
    }
}

// ---------------------------------------------------------------------------
// K3: out = (c1+c2) @ Wo^T + bo   (fp32)
// ---------------------------------------------------------------------------
__global__ __launch_bounds__(256) void k_oproj(
    const float* __restrict__ c1, const float* __restrict__ c2,
    const float* __restrict__ Wo, const float* __restrict__ bo,
    float* __restrict__ outp)
{
    __shared__ float sA[16][132];
    __shared__ float sB[16][132];
    const int tid = threadIdx.x;
    const int tx = tid & 15, ty = tid >> 4;
    const int eb = blockIdx.x * 128;
    const int nb = blockIdx.y * 128;

    float acc[8][8];
    #pragma unroll
    for (int i = 0; i < 8; ++i)
        #pragma unroll
        for (int j = 0; j < 8; ++j) acc[i][j] = 0.0f;

    for (int kb = 0; kb < 1024; kb += 16) {
        #pragma unroll
        for (int l = 0; l < 2; ++l) {
            int fid = tid + l * 256;
            int r = fid >> 2, c4 = (fid & 3) * 4;
            size_t aoff = (size_t)(nb + r) * 1024 + kb + c4;
            float4 a1 = *(const float4*)(c1 + aoff);
            float4 a2 = *(const float4*)(c2 + aoff);
            sA[c4+0][r] = a1.x + a2.x; sA[c4+1][r] = a1.y + a2.y;
            sA[c4+2][r] = a1.z + a2.z; sA[c4+3][r] = a1.w + a2.w;
            float4 wv = *(const float4*)(Wo + (size_t)(eb + r) * 1024 + kb + c4);
            sB[c4+0][r] = wv.x; sB[c4+1][r] = wv.y; sB[c4+2][r] = wv.z; sB[c4+3][r] = wv.w;
        }
        __syncthreads();
        #pragma unroll
        for (int kk = 0; kk < 16; ++kk) {
            float a[8], b[8];
            *(float4*)&a[0] = *(const float4*)&sA[kk][ty*8];
            *(float4*)&a[4] = *(const float4*)&sA[kk][ty*8+4];
            *(float4*)&b[0] = *(const float4*)&sB[kk][tx*8];
            *(float4*)&b[4] = *(const float4*)&sB[kk][tx*8+4];
            #pragma unroll
            for (int i = 0; i < 8; ++i)
                #pragma unroll
                for (int j = 0; j < 8; ++j) acc[i][j] += a[i] * b[j];
        }
        __syncthreads();
    }
    float bb[8];
    *(float4*)&bb[0] = *(const float4*)(bo + eb + tx*8);
    *(float4*)&bb[4] = *(const float4*)(bo + eb + tx*8 + 4);
    #pragma unroll
    for (int i = 0; i < 8; ++i) {
        int n = nb + ty*8 + i;
        #pragma unroll
        for (int jj = 0; jj < 2; ++jj) {
            float4 o;
            o.x = acc[i][jj*4+0] + bb[jj*4+0];
            o.y = acc[i][jj*4+1] + bb[jj*4+1];
            o.z = acc[i][jj*4+2] + bb[jj*4+2];
            o.w = acc[i][jj*4+3] + bb[jj*4+3];
            *(float4*)(outp + (size_t)n * 1024 + eb + tx*8 + jj*4) = o;
        }
    }
}

// ---------------------------------------------------------------------------
extern "C" void kernel_launch(void* const* d_in, const int* in_sizes, int n_in,
                              void* d_out, int out_size, void* d_ws, size_t ws_size,
                              hipStream_t stream) {
    const float* hs   = (const float*)d_in[0];
    const float* Wq   = (const float*)d_in[1];
    const float* bq   = (const float*)d_in[2];
    const float* Wk   = (const float*)d_in[3];
    const float* bk   = (const float*)d_in[4];
    const float* Wv   = (const float*)d_in[5];
    const float* bv   = (const float*)d_in[6];
    const float* Wo   = (const float*)d_in[7];
    const float* bo   = (const float*)d_in[8];
    const float* relk = (const float*)d_in[9];
    const float* relv = (const float*)d_in[10];
    float* out = (float*)d_out;

    float* ws = (float*)d_ws;
    float* qs = ws;
    float* ks = ws + 4194304;
    float* vs = ws + 8388608;
    float* c1 = ws + 12582912;
    float* c2 = ws + 16777216;

    k_qkv  <<<dim3(8, 32, 3), 256, 0, stream>>>(hs, Wq, bq, Wk, bk, Wv, bv, qs, ks, vs);
    k_fused<<<dim3(64, 64),   256, 0, stream>>>(qs, ks, vs, relk, relv, c1, c2);
    k_oproj<<<dim3(8, 32),    256, 0, stream>>>(c1, c2, Wo, bo, out);
}

// Round 7
// 814.569 us; speedup vs baseline: 16.4513x; 1.4647x over previous
//
#include <hip/hip_runtime.h>
#include <hip/hip_bf16.h>

// B=4, T=1024, E=1024, H=16, D=64, P=257.  Slot s = b*16+h (64 slots).
// Quirk: score slot m uses rel-K of slot pm=(m&15)*4+(m>>4); attn of slot m
// feeds w2 output of slot m2=(m&3)*16+(m>>2).
// R7: all MFMA operands pre-laid-out in bf16 global (qb/kb row-major, vt=V^T,
// relkB, relvT). k_fused loads A/B fragments straight from global (L2-hot);
// LDS only for P round-trip, gathered-G, R-table, softmax partials.

typedef __attribute__((ext_vector_type(8))) short short8;
typedef __attribute__((ext_vector_type(4))) float f32x4;

__device__ __forceinline__ float bf16f(unsigned int u) {
    union { unsigned int i; float f; } v; v.i = u << 16; return v.f;
}
__device__ __forceinline__ unsigned short f2b(float x) {
    __hip_bfloat16 h = __float2bfloat16(x);
    return *reinterpret_cast<unsigned short*>(&h);
}

// ---------------------------------------------------------------------------
// K1: fused QKV projection (fp32 math).  z=0: qb bf16 (scaled 1/8, row-major
// slot layout), z=1: kb bf16 row-major, z=2: vt bf16 TRANSPOSED [s][d][t]
// (transpose free in registers: acc tile has t contiguous per d-column).
// ---------------------------------------------------------------------------
__global__ __launch_bounds__(256) void k_qkv(
    const float* __restrict__ hs,
    const float* __restrict__ Wq, const float* __restrict__ bq,
    const float* __restrict__ Wk, const float* __restrict__ bk,
    const float* __restrict__ Wv, const float* __restrict__ bv,
    unsigned short* __restrict__ qb, unsigned short* __restrict__ kb,
    unsigned short* __restrict__ vt)
{
    __shared__ float sA[16][132];
    __shared__ float sB[16][132];
    const int tid = threadIdx.x;
    const int tx = tid & 15, ty = tid >> 4;
    const int eb = blockIdx.x * 128;
    const int nb = blockIdx.y * 128;
    const int z = blockIdx.z;
    const float* W    = (z == 0) ? Wq : (z == 1) ? Wk : Wv;
    const float* bias = (z == 0) ? bq : (z == 1) ? bk : bv;
    const float scale = (z == 0) ? 0.125f : 1.0f;

    float acc[8][8];
    #pragma unroll
    for (int i = 0; i < 8; ++i)
        #pragma unroll
        for (int j = 0; j < 8; ++j) acc[i][j] = 0.0f;

    for (int kbk = 0; kbk < 1024; kbk += 16) {
        #pragma unroll
        for (int l = 0; l < 2; ++l) {
            int fid = tid + l * 256;
            int r = fid >> 2, c4 = (fid & 3) * 4;
            float4 av = *(const float4*)(hs + (size_t)(nb + r) * 1024 + kbk + c4);
            sA[c4+0][r] = av.x; sA[c4+1][r] = av.y; sA[c4+2][r] = av.z; sA[c4+3][r] = av.w;
            float4 wv = *(const float4*)(W + (size_t)(eb + r) * 1024 + kbk + c4);
            sB[c4+0][r] = wv.x; sB[c4+1][r] = wv.y; sB[c4+2][r] = wv.z; sB[c4+3][r] = wv.w;
        }
        __syncthreads();
        #pragma unroll
        for (int kk = 0; kk < 16; ++kk) {
            float a[8], b[8];
            *(float4*)&a[0] = *(const float4*)&sA[kk][ty*8];
            *(float4*)&a[4] = *(const float4*)&sA[kk][ty*8+4];
            *(float4*)&b[0] = *(const float4*)&sB[kk][tx*8];
            *(float4*)&b[4] = *(const float4*)&sB[kk][tx*8+4];
            #pragma unroll
            for (int i = 0; i < 8; ++i)
                #pragma unroll
                for (int j = 0; j < 8; ++j) acc[i][j] += a[i] * b[j];
        }
        __syncthreads();
    }
    float bb[8];
    *(float4*)&bb[0] = *(const float4*)(bias + eb + tx*8);
    *(float4*)&bb[4] = *(const float4*)(bias + eb + tx*8 + 4);

    if (z == 2) {
        // transposed store: for each of 8 d-cols, pack 8 consecutive t-rows
        #pragma unroll
        for (int j = 0; j < 8; ++j) {
            int e0 = eb + tx*8 + j;
            int s = (nb >> 10) * 16 + (e0 >> 6);
            int d = e0 & 63;
            int t = (nb & 1023) + ty*8;
            unsigned short tmp[8];
            #pragma unroll
            for (int i = 0; i < 8; ++i) tmp[i] = f2b(acc[i][j] + bb[j]);
            *(uint4*)(vt + (((size_t)(s*64 + d)) << 10) + t) = *(const uint4*)tmp;
        }
    } else {
        unsigned short* outb = (z == 0) ? qb : kb;
        #pragma unroll
        for (int i = 0; i < 8; ++i) {
            int n = nb + ty*8 + i;
            int s = (n >> 10) * 16 + ((eb + tx*8) >> 6);
            int t = n & 1023;
            int d0 = (eb + tx*8) & 63;
            unsigned short tmp[8];
            #pragma unroll
            for (int j = 0; j < 8; ++j) tmp[j] = f2b((acc[i][j] + bb[j]) * scale);
            *(uint4*)(outb + (((size_t)(s*1024 + t)) << 6) + d0) = *(const uint4*)tmp;
        }
    }
}

// ---------------------------------------------------------------------------
// K1b: rel-table prep.  relkB = bf16 relk row-major [272][64] (rows>=257 zero);
// relvT = bf16 relv^T [64][264] (cols>=257 zero; +128 shorts tail pad
// uninitialized — only ever multiplied by zero G columns).
// ---------------------------------------------------------------------------
__global__ __launch_bounds__(256) void k_rel(
    const float* __restrict__ relk, const float* __restrict__ relv,
    unsigned short* __restrict__ relkB, unsigned short* __restrict__ relvT)
{
    const int tid = threadIdx.x;
    for (int i = tid; i < 272*64; i += 256) {
        int j = i >> 6;
        relkB[i] = (j < 257) ? f2b(relk[i]) : (unsigned short)0;
    }
    {
        int d = tid >> 2, grp = tid & 3;
        for (int jj = 0; jj < 66; ++jj) {
            int j = grp*66 + jj;
            if (j < 264)
                relvT[d*264 + j] = (j < 257) ? f2b(relv[j*64 + d]) : (unsigned short)0;
        }
    }
}

// ---------------------------------------------------------------------------
// K2: MFMA flash attention, global-operand fragments.
// Block = (slot m, 16 q-rows), 4 waves; wave w owns output cols w*16+lq.
// ---------------------------------------------------------------------------
__global__ __launch_bounds__(256) void k_fused(
    const unsigned short* __restrict__ qb, const unsigned short* __restrict__ kb,
    const unsigned short* __restrict__ vt, const unsigned short* __restrict__ relkB,
    const unsigned short* __restrict__ relvT, const float* __restrict__ relv,
    float* __restrict__ c1, float* __restrict__ c2)
{
    __shared__ __align__(16) unsigned short sP[16][72];    //  2304 B  P bf16 [q][k]
    __shared__ __align__(16) unsigned short sG[16][104];   //  3328 B  gathered P
    __shared__ unsigned short sR[16][273];                 //  8736 B  rel-K bias (odd stride: bank spread)
    __shared__ float sPartMax[4][16];
    __shared__ float sPartSum[4][16];                      //  => ~14.9 KB

    const int tid = threadIdx.x;
    const int m  = blockIdx.y;
    const int q0 = blockIdx.x * 16;
    const int pm = (m & 15) * 4 + (m >> 4);
    const int m2 = (m & 3) * 16 + (m >> 2);
    const int w    = tid >> 6;
    const int lane = tid & 63;
    const int lq   = lane & 15;
    const int quad = lane >> 4;

    // ---- Phase A: R table via MFMA: R[q][j] = Qb[pm][q]·relkB[j] ----
    {
        const unsigned short* qpm = qb + (((size_t)(pm*1024 + q0 + lq)) << 6);
        short8 apm0 = *(const short8*)(qpm + quad*8);
        short8 apm1 = *(const short8*)(qpm + 32 + quad*8);
        for (int jt = w; jt < 17; jt += 4) {
            const unsigned short* rkb = relkB + (size_t)(jt*16 + lq) * 64;
            short8 b0 = *(const short8*)(rkb + quad*8);
            short8 b1 = *(const short8*)(rkb + 32 + quad*8);
            f32x4 cr = {0,0,0,0};
            cr = __builtin_amdgcn_mfma_f32_16x16x32_bf16(apm0, b0, cr, 0, 0, 0);
            cr = __builtin_amdgcn_mfma_f32_16x16x32_bf16(apm1, b1, cr, 0, 0, 0);
            #pragma unroll
            for (int i = 0; i < 4; ++i) sR[quad*4 + i][jt*16 + lq] = f2b(cr[i]);
        }
    }
    __syncthreads();

    // hoisted A-frags (Q[m]) and rel-V edge columns
    const unsigned short* qm = qb + (((size_t)(m*1024 + q0 + lq)) << 6);
    const short8 aq0 = *(const short8*)(qm + quad*8);
    const short8 aq1 = *(const short8*)(qm + 32 + quad*8);
    const float relE0 = relv[w*16 + lq];
    const float relE1 = relv[256*64 + w*16 + lq];

    float mrow[4], lrow[4];
    f32x4 c1a = {0,0,0,0}, c2a = {0,0,0,0};
    #pragma unroll
    for (int i = 0; i < 4; ++i) { mrow[i] = -1e30f; lrow[i] = 0.0f; }

    #pragma unroll 1
    for (int kt = 0; kt < 16; ++kt) {
        const int k0 = kt * 64;
        const int jminU = q0 - k0 - 63 + 128;
        const int jmaxU = q0 - k0 + 15 + 128;
        const bool fully_low  = (jmaxU <= 0);
        const bool fully_high = (jminU >= 256);
        const bool clipped = fully_low || fully_high;
        const bool pure_interior = (jminU >= 0) && (jmaxU <= 256);
        const int jlo8 = (jminU < 0) ? 0 : (jminU & ~7);

        if (!clipped) {  // zero G (prev needG tile ended with a barrier)
            #pragma unroll
            for (int i = 0; i < 4; ++i) {
                int idx = tid + i * 256;
                if (idx < 832) ((unsigned int*)sG)[idx] = 0u;
            }
        }

        // ---- QK^T MFMA (B-frags direct from kb) ----
        const unsigned short* krow = kb + (((size_t)(m*1024 + k0 + w*16 + lq)) << 6);
        short8 bk0 = *(const short8*)(krow + quad*8);
        short8 bk1 = *(const short8*)(krow + 32 + quad*8);
        f32x4 s4 = {0,0,0,0};
        s4 = __builtin_amdgcn_mfma_f32_16x16x32_bf16(aq0, bk0, s4, 0, 0, 0);
        s4 = __builtin_amdgcn_mfma_f32_16x16x32_bf16(aq1, bk1, s4, 0, 0, 0);

        float sc[4], mloc[4];
        const int kcol = k0 + w*16 + lq;
        #pragma unroll
        for (int i = 0; i < 4; ++i) {
            int row = quad*4 + i;
            int dist = (q0 + row) - kcol;
            int jd = dist < -128 ? 0 : (dist > 128 ? 256 : dist + 128);
            sc[i] = s4[i] + bf16f(sR[row][jd]);
            mloc[i] = sc[i];
        }
        #pragma unroll
        for (int off = 1; off < 16; off <<= 1)
            #pragma unroll
            for (int i = 0; i < 4; ++i)
                mloc[i] = fmaxf(mloc[i], __shfl_xor(mloc[i], off, 64));
        if (lq == 0) {
            #pragma unroll
            for (int i = 0; i < 4; ++i) sPartMax[w][quad*4 + i] = mloc[i];
        }
        __syncthreads();   // B2

        float mnew[4], alpha[4], e[4], psum[4];
        #pragma unroll
        for (int i = 0; i < 4; ++i) {
            int row = quad*4 + i;
            float ma = fmaxf(fmaxf(sPartMax[0][row], sPartMax[1][row]),
                             fmaxf(sPartMax[2][row], sPartMax[3][row]));
            mnew[i] = fmaxf(mrow[i], ma);
            alpha[i] = exp2f((mrow[i] - mnew[i]) * 1.44269504f);
            e[i] = exp2f((sc[i] - mnew[i]) * 1.44269504f);
            psum[i] = e[i];
        }
        #pragma unroll
        for (int off = 1; off < 16; off <<= 1)
            #pragma unroll
            for (int i = 0; i < 4; ++i)
                psum[i] += __shfl_xor(psum[i], off, 64);
        if (lq == 0) {
            #pragma unroll
            for (int i = 0; i < 4; ++i) sPartSum[w][quad*4 + i] = psum[i];
        }
        #pragma unroll
        for (int i = 0; i < 4; ++i) sP[quad*4 + i][w*16 + lq] = f2b(e[i]);
        __syncthreads();   // B3

        float sAll[4];
        #pragma unroll
        for (int i = 0; i < 4; ++i) {
            int row = quad*4 + i;
            sAll[i] = sPartSum[0][row] + sPartSum[1][row]
                    + sPartSum[2][row] + sPartSum[3][row];
            lrow[i] = lrow[i] * alpha[i] + sAll[i];
            mrow[i] = mnew[i];
            c1a[i] *= alpha[i];
            c2a[i] *= alpha[i];
        }

        // ---- P·V MFMA (A from sP LDS, B direct from vt) ----
        {
            short8 ap0 = *(const short8*)&sP[lq][quad*8];
            short8 ap1 = *(const short8*)&sP[lq][32 + quad*8];
            const unsigned short* vrow = vt + (((size_t)(m*64 + w*16 + lq)) << 10) + k0;
            short8 bv0 = *(const short8*)(vrow + quad*8);
            short8 bv1 = *(const short8*)(vrow + 32 + quad*8);
            c1a = __builtin_amdgcn_mfma_f32_16x16x32_bf16(ap0, bv0, c1a, 0, 0, 0);
            c1a = __builtin_amdgcn_mfma_f32_16x16x32_bf16(ap1, bv1, c1a, 0, 0, 0);
        }

        // ---- rel-V contribution ----
        if (clipped) {
            float re = fully_low ? relE0 : relE1;
            #pragma unroll
            for (int i = 0; i < 4; ++i) c2a[i] += sAll[i] * re;
        } else {
            if (pure_interior) {
                #pragma unroll
                for (int i2 = 0; i2 < 4; ++i2) {
                    int idx = tid + i2 * 256;
                    int q = idx >> 6, k2 = idx & 63;
                    sG[q][(q0 + q) - (k0 + k2) + 128 - jlo8] = sP[q][k2];
                }
            } else if (tid < 64) {
                int q = tid >> 2, part = tid & 3;
                float e0 = 0.0f, e256 = 0.0f;
                #pragma unroll 1
                for (int kk = part*16; kk < part*16 + 16; ++kk) {
                    int dist = (q0 + q) - (k0 + kk);
                    if (dist <= -128)      e0   += bf16f(sP[q][kk]);
                    else if (dist >= 128)  e256 += bf16f(sP[q][kk]);
                    else                   sG[q][dist + 128 - jlo8] = sP[q][kk];
                }
                e0   += __shfl_xor(e0, 1, 64);   e0   += __shfl_xor(e0, 2, 64);
                e256 += __shfl_xor(e256, 1, 64); e256 += __shfl_xor(e256, 2, 64);
                if (part == 0) {
                    if (jminU < 0)   sG[q][0]           = f2b(e0);
                    if (jmaxU > 256) sG[q][256 - jlo8]  = f2b(e256);
                }
            }
            __syncthreads();   // B4 (needG is block-uniform)
            short8 ag0 = *(const short8*)&sG[lq][quad*8];
            short8 ag1 = *(const short8*)&sG[lq][32 + quad*8];
            short8 ag2 = *(const short8*)&sG[lq][64 + quad*8];
            const unsigned short* rrow = relvT + (size_t)(w*16 + lq) * 264 + jlo8;
            short8 br0 = *(const short8*)(rrow + quad*8);
            short8 br1 = *(const short8*)(rrow + 32 + quad*8);
            short8 br2 = *(const short8*)(rrow + 64 + quad*8);
            c2a = __builtin_amdgcn_mfma_f32_16x16x32_bf16(ag0, br0, c2a, 0, 0, 0);
            c2a = __builtin_amdgcn_mfma_f32_16x16x32_bf16(ag1, br1, c2a, 0, 0, 0);
            c2a = __builtin_amdgcn_mfma_f32_16x16x32_bf16(ag2, br2, c2a, 0, 0, 0);
            __syncthreads();   // B5: protect sP/sG before next tile
        }
    }

    // ---- epilogue (C layout: row=quad*4+i, col=w*16+lq) ----
    const int b1 = m >> 4,  h1 = m & 15;
    const int b2 = m2 >> 4, h2 = m2 & 15;
    #pragma unroll
    for (int i = 0; i < 4; ++i) {
        int row = quad*4 + i;
        float inv = 1.0f / lrow[i];
        int col = w*16 + lq;
        c1[(size_t)(b1*1024 + q0 + row) * 1024 + h1*64 + col] = c1a[i] * inv;
        c2[(size_t)(b2*1024 + q0 + row) * 1024 + h2*64 + col] = c2a[i] * inv;
    }
}

// ---------------------------------------------------------------------------
// K3: out = (c1+c2) @ Wo^T + bo   (fp32)
// ---------------------------------------------------------------------------
__global__ __launch_bounds__(256) void k_oproj(
    const float* __restrict__ c1, const float* __restrict__ c2,
    const float* __restrict__ Wo, const float* __restrict__ bo,
    float* __restrict__ outp)
{
    __shared__ float sA[16][132];
    __shared__ float sB[16][132];
    const int tid = threadIdx.x;
    const int tx = tid & 15, ty = tid >> 4;
    const int eb = blockIdx.x * 128;
    const int nb = blockIdx.y * 128;

    float acc[8][8];
    #pragma unroll
    for (int i = 0; i < 8; ++i)
        #pragma unroll
        for (int j = 0; j < 8; ++j) acc[i][j] = 0.0f;

    for (int kb = 0; kb < 1024; kb += 16) {
        #pragma unroll
        for (int l = 0; l < 2; ++l) {
            int fid = tid + l * 256;
            int r = fid >> 2, c4 = (fid & 3) * 4;
            size_t aoff = (size_t)(nb + r) * 1024 + kb + c4;
            float4 a1 = *(const float4*)(c1 + aoff);
            float4 a2 = *(const float4*)(c2 + aoff);
            sA[c4+0][r] = a1.x + a2.x; sA[c4+1][r] = a1.y + a2.y;
            sA[c4+2][r] = a1.z + a2.z; sA[c4+3][r] = a1.w + a2.w;
            float4 wv = *(const float4*)(Wo + (size_t)(eb + r) * 1024 + kb + c4);
            sB[c4+0][r] = wv.x; sB[c4+1][r] = wv.y; sB[c4+2][r] = wv.z; sB[c4+3][r] = wv.w;
        }
        __syncthreads();
        #pragma unroll
        for (int kk = 0; kk < 16; ++kk) {
            float a[8], b[8];
            *(float4*)&a[0] = *(const float4*)&sA[kk][ty*8];
            *(float4*)&a[4] = *(const float4*)&sA[kk][ty*8+4];
            *(float4*)&b[0] = *(const float4*)&sB[kk][tx*8];
            *(float4*)&b[4] = *(const float4*)&sB[kk][tx*8+4];
            #pragma unroll
            for (int i = 0; i < 8; ++i)
                #pragma unroll
                for (int j = 0; j < 8; ++j) acc[i][j] += a[i] * b[j];
        }
        __syncthreads();
    }
    float bb[8];
    *(float4*)&bb[0] = *(const float4*)(bo + eb + tx*8);
    *(float4*)&bb[4] = *(const float4*)(bo + eb + tx*8 + 4);
    #pragma unroll
    for (int i = 0; i < 8; ++i) {
        int n = nb + ty*8 + i;
        #pragma unroll
        for (int jj = 0; jj < 2; ++jj) {
            float4 o;
            o.x = acc[i][jj*4+0] + bb[jj*4+0];
            o.y = acc[i][jj*4+1] + bb[jj*4+1];
            o.z = acc[i][jj*4+2] + bb[jj*4+2];
            o.w = acc[i][jj*4+3] + bb[jj*4+3];
            *(float4*)(outp + (size_t)n * 1024 + eb + tx*8 + jj*4) = o;
        }
    }
}

// ---------------------------------------------------------------------------
extern "C" void kernel_launch(void* const* d_in, const int* in_sizes, int n_in,
                              void* d_out, int out_size, void* d_ws, size_t ws_size,
                              hipStream_t stream) {
    const float* hs   = (const float*)d_in[0];
    const float* Wq   = (const float*)d_in[1];
    const float* bq   = (const float*)d_in[2];
    const float* Wk   = (const float*)d_in[3];
    const float* bk   = (const float*)d_in[4];
    const float* Wv   = (const float*)d_in[5];
    const float* bv   = (const float*)d_in[6];
    const float* Wo   = (const float*)d_in[7];
    const float* bo   = (const float*)d_in[8];
    const float* relk = (const float*)d_in[9];
    const float* relv = (const float*)d_in[10];
    float* out = (float*)d_out;

    // Workspace (shorts): qb 4M, kb 4M, vt 4M, relkB 17408, relvT 16912+128pad;
    // then c1/c2 fp32 4M floats each.  Total ~58.8 MB.
    unsigned short* wsu = (unsigned short*)d_ws;
    unsigned short* qbp   = wsu;
    unsigned short* kbp   = wsu + 4194304;
    unsigned short* vtp   = wsu + 8388608;
    unsigned short* relkB = wsu + 12582912;
    unsigned short* relvT = wsu + 12600320;
    float* c1 = (float*)(wsu + 12617360);
    float* c2 = c1 + 4194304;

    k_qkv  <<<dim3(8, 32, 3), 256, 0, stream>>>(hs, Wq, bq, Wk, bk, Wv, bv, qbp, kbp, vtp);
    k_rel  <<<dim3(1),        256, 0, stream>>>(relk, relv, relkB, relvT);
    k_fused<<<dim3(64, 64),   256, 0, stream>>>(qbp, kbp, vtp, relkB, relvT, relv, c1, c2);
    k_oproj<<<dim3(8, 32),    256, 0, stream>>>(c1, c2, Wo, bo, out);
}

// Round 8
// 555.092 us; speedup vs baseline: 24.1415x; 1.4674x over previous
//
#include <hip/hip_runtime.h>
#include <hip/hip_bf16.h>

// B=4, T=1024, E=1024, H=16, D=64, P=257.  Slot s = b*16+h (64 slots).
// Quirk: score slot m uses rel-K of slot pm=(m&15)*4+(m>>4); attn of slot m
// feeds w2 output of slot m2=(m&3)*16+(m>>2).
// R8: projection GEMMs -> bf16 MFMA with hi/lo split (C = AhBh + AlBh + AhBl,
// near-fp32 accuracy).  k_split pre-splits hs and W matrices; k_gemm_o splits
// (c1+c2) on the fly.  k_fused / k_rel unchanged from R7.

typedef __attribute__((ext_vector_type(8))) short short8;
typedef __attribute__((ext_vector_type(4))) float f32x4;

__device__ __forceinline__ float bf16f(unsigned int u) {
    union { unsigned int i; float f; } v; v.i = u << 16; return v.f;
}
__device__ __forceinline__ unsigned short f2b(float x) {
    __hip_bfloat16 h = __float2bfloat16(x);
    return *reinterpret_cast<unsigned short*>(&h);
}

// ---------------------------------------------------------------------------
// K0: split fp32 -> (hi, lo) bf16.   n4 = count of float4s.
// ---------------------------------------------------------------------------
__global__ __launch_bounds__(256) void k_split(
    const float* __restrict__ src, unsigned short* __restrict__ hi,
    unsigned short* __restrict__ lo, int n4)
{
    int stride = gridDim.x * 256;
    for (int i = blockIdx.x * 256 + threadIdx.x; i < n4; i += stride) {
        float4 x = *(const float4*)(src + i*4);
        unsigned short h[4], l[4];
        float xs[4] = {x.x, x.y, x.z, x.w};
        #pragma unroll
        for (int j = 0; j < 4; ++j) {
            h[j] = f2b(xs[j]);
            l[j] = f2b(xs[j] - bf16f(h[j]));
        }
        *(ushort4*)(hi + i*4) = make_ushort4(h[0], h[1], h[2], h[3]);
        *(ushort4*)(lo + i*4) = make_ushort4(l[0], l[1], l[2], l[3]);
    }
}

// ---------------------------------------------------------------------------
// K1: QKV projection via split-bf16 MFMA.  C[n,e] = hs[n,:]·W[e,:] + b[e].
// z=0 -> qb (×1/8), z=1 -> kb, z=2 -> vt (transposed slot layout).
// 128x128 tile, BK=32, 4 waves (2x2), 4x4 MFMA tiles/wave, 3 MFMAs per tile.
// ---------------------------------------------------------------------------
__global__ __launch_bounds__(256) void k_gemm_qkv(
    const unsigned short* __restrict__ hh, const unsigned short* __restrict__ hl,
    const unsigned short* __restrict__ wqh, const unsigned short* __restrict__ wql,
    const unsigned short* __restrict__ wkh, const unsigned short* __restrict__ wkl,
    const unsigned short* __restrict__ wvh, const unsigned short* __restrict__ wvl,
    const float* __restrict__ bq, const float* __restrict__ bk,
    const float* __restrict__ bv,
    unsigned short* __restrict__ qb, unsigned short* __restrict__ kb,
    unsigned short* __restrict__ vt)
{
    __shared__ __align__(16) unsigned short sAh[128][48];
    __shared__ __align__(16) unsigned short sAl[128][48];
    __shared__ __align__(16) unsigned short sBh[128][48];
    __shared__ __align__(16) unsigned short sBl[128][48];
    const int tid = threadIdx.x;
    const int eb = blockIdx.x * 128, nb = blockIdx.y * 128, z = blockIdx.z;
    const unsigned short* Bh = (z == 0) ? wqh : (z == 1) ? wkh : wvh;
    const unsigned short* Bl = (z == 0) ? wql : (z == 1) ? wkl : wvl;
    const float* bias = (z == 0) ? bq : (z == 1) ? bk : bv;
    const float scale = (z == 0) ? 0.125f : 1.0f;
    const int w = tid >> 6, lane = tid & 63, lq = lane & 15, quad = lane >> 4;
    const int wr = w >> 1, wc = w & 1;
    const int srow = tid >> 2, sc8 = (tid & 3) * 8;

    f32x4 acc[4][4];
    #pragma unroll
    for (int i = 0; i < 4; ++i)
        #pragma unroll
        for (int j = 0; j < 4; ++j) acc[i][j] = (f32x4){0,0,0,0};

    for (int k0 = 0; k0 < 1024; k0 += 32) {
        uint4 a0h = *(const uint4*)(hh + (size_t)(nb + srow) * 1024 + k0 + sc8);
        uint4 a1h = *(const uint4*)(hh + (size_t)(nb + srow + 64) * 1024 + k0 + sc8);
        uint4 a0l = *(const uint4*)(hl + (size_t)(nb + srow) * 1024 + k0 + sc8);
        uint4 a1l = *(const uint4*)(hl + (size_t)(nb + srow + 64) * 1024 + k0 + sc8);
        uint4 b0h = *(const uint4*)(Bh + (size_t)(eb + srow) * 1024 + k0 + sc8);
        uint4 b1h = *(const uint4*)(Bh + (size_t)(eb + srow + 64) * 1024 + k0 + sc8);
        uint4 b0l = *(const uint4*)(Bl + (size_t)(eb + srow) * 1024 + k0 + sc8);
        uint4 b1l = *(const uint4*)(Bl + (size_t)(eb + srow + 64) * 1024 + k0 + sc8);
        __syncthreads();   // prev-iter reads done before overwrite
        *(uint4*)&sAh[srow][sc8] = a0h;  *(uint4*)&sAh[srow + 64][sc8] = a1h;
        *(uint4*)&sAl[srow][sc8] = a0l;  *(uint4*)&sAl[srow + 64][sc8] = a1l;
        *(uint4*)&sBh[srow][sc8] = b0h;  *(uint4*)&sBh[srow + 64][sc8] = b1h;
        *(uint4*)&sBl[srow][sc8] = b0l;  *(uint4*)&sBl[srow + 64][sc8] = b1l;
        __syncthreads();

        short8 ah[4], al[4], bhf[4], blf[4];
        #pragma unroll
        for (int t = 0; t < 4; ++t) {
            ah[t]  = *(const short8*)&sAh[wr*64 + t*16 + lq][quad*8];
            al[t]  = *(const short8*)&sAl[wr*64 + t*16 + lq][quad*8];
            bhf[t] = *(const short8*)&sBh[wc*64 + t*16 + lq][quad*8];
            blf[t] = *(const short8*)&sBl[wc*64 + t*16 + lq][quad*8];
        }
        #pragma unroll
        for (int ti = 0; ti < 4; ++ti)
            #pragma unroll
            for (int tj = 0; tj < 4; ++tj) {
                acc[ti][tj] = __builtin_amdgcn_mfma_f32_16x16x32_bf16(ah[ti], bhf[tj], acc[ti][tj], 0, 0, 0);
                acc[ti][tj] = __builtin_amdgcn_mfma_f32_16x16x32_bf16(al[ti], bhf[tj], acc[ti][tj], 0, 0, 0);
                acc[ti][tj] = __builtin_amdgcn_mfma_f32_16x16x32_bf16(ah[ti], blf[tj], acc[ti][tj], 0, 0, 0);
            }
    }

    // epilogue: C row = n-dim (quad*4+i), col = e-dim (lq)
    #pragma unroll
    for (int tj = 0; tj < 4; ++tj) {
        int e = eb + wc*64 + tj*16 + lq;
        float bb = bias[e];
        int h = e >> 6, d = e & 63;
        #pragma unroll
        for (int ti = 0; ti < 4; ++ti) {
            #pragma unroll
            for (int i = 0; i < 4; ++i) {
                int n = nb + wr*64 + ti*16 + quad*4 + i;
                int bidx = n >> 10, t = n & 1023;
                int s = bidx*16 + h;
                float val = (acc[ti][tj][i] + bb) * scale;
                if (z == 2)
                    vt[(((size_t)(s*64 + d)) << 10) + t] = f2b(val);
                else if (z == 0)
                    qb[(((size_t)(s*1024 + t)) << 6) + d] = f2b(val);
                else
                    kb[(((size_t)(s*1024 + t)) << 6) + d] = f2b(val);
            }
        }
    }
}

// ---------------------------------------------------------------------------
// K1b: rel-table prep (unchanged from R7).
// ---------------------------------------------------------------------------
__global__ __launch_bounds__(256) void k_rel(
    const float* __restrict__ relk, const float* __restrict__ relv,
    unsigned short* __restrict__ relkB, unsigned short* __restrict__ relvT)
{
    const int tid = threadIdx.x;
    for (int i = tid; i < 272*64; i += 256) {
        int j = i >> 6;
        relkB[i] = (j < 257) ? f2b(relk[i]) : (unsigned short)0;
    }
    {
        int d = tid >> 2, grp = tid & 3;
        for (int jj = 0; jj < 66; ++jj) {
            int j = grp*66 + jj;
            if (j < 264)
                relvT[d*264 + j] = (j < 257) ? f2b(relv[j*64 + d]) : (unsigned short)0;
        }
    }
}

// ---------------------------------------------------------------------------
// K2: MFMA flash attention (unchanged from R7).
// ---------------------------------------------------------------------------
__global__ __launch_bounds__(256) void k_fused(
    const unsigned short* __restrict__ qb, const unsigned short* __restrict__ kb,
    const unsigned short* __restrict__ vt, const unsigned short* __restrict__ relkB,
    const unsigned short* __restrict__ relvT, const float* __restrict__ relv,
    float* __restrict__ c1, float* __restrict__ c2)
{
    __shared__ __align__(16) unsigned short sP[16][72];
    __shared__ __align__(16) unsigned short sG[16][104];
    __shared__ unsigned short sR[16][273];
    __shared__ float sPartMax[4][16];
    __shared__ float sPartSum[4][16];

    const int tid = threadIdx.x;
    const int m  = blockIdx.y;
    const int q0 = blockIdx.x * 16;
    const int pm = (m & 15) * 4 + (m >> 4);
    const int m2 = (m & 3) * 16 + (m >> 2);
    const int w    = tid >> 6;
    const int lane = tid & 63;
    const int lq   = lane & 15;
    const int quad = lane >> 4;

    {
        const unsigned short* qpm = qb + (((size_t)(pm*1024 + q0 + lq)) << 6);
        short8 apm0 = *(const short8*)(qpm + quad*8);
        short8 apm1 = *(const short8*)(qpm + 32 + quad*8);
        for (int jt = w; jt < 17; jt += 4) {
            const unsigned short* rkb = relkB + (size_t)(jt*16 + lq) * 64;
            short8 b0 = *(const short8*)(rkb + quad*8);
            short8 b1 = *(const short8*)(rkb + 32 + quad*8);
            f32x4 cr = {0,0,0,0};
            cr = __builtin_amdgcn_mfma_f32_16x16x32_bf16(apm0, b0, cr, 0, 0, 0);
            cr = __builtin_amdgcn_mfma_f32_16x16x32_bf16(apm1, b1, cr, 0, 0, 0);
            #pragma unroll
            for (int i = 0; i < 4; ++i) sR[quad*4 + i][jt*16 + lq] = f2b(cr[i]);
        }
    }
    __syncthreads();

    const unsigned short* qm = qb + (((size_t)(m*1024 + q0 + lq)) << 6);
    const short8 aq0 = *(const short8*)(qm + quad*8);
    const short8 aq1 = *(const short8*)(qm + 32 + quad*8);
    const float relE0 = relv[w*16 + lq];
    const float relE1 = relv[256*64 + w*16 + lq];

    float mrow[4], lrow[4];
    f32x4 c1a = {0,0,0,0}, c2a = {0,0,0,0};
    #pragma unroll
    for (int i = 0; i < 4; ++i) { mrow[i] = -1e30f; lrow[i] = 0.0f; }

    #pragma unroll 1
    for (int kt = 0; kt < 16; ++kt) {
        const int k0 = kt * 64;
        const int jminU = q0 - k0 - 63 + 128;
        const int jmaxU = q0 - k0 + 15 + 128;
        const bool fully_low  = (jmaxU <= 0);
        const bool fully_high = (jminU >= 256);
        const bool clipped = fully_low || fully_high;
        const bool pure_interior = (jminU >= 0) && (jmaxU <= 256);
        const int jlo8 = (jminU < 0) ? 0 : (jminU & ~7);

        if (!clipped) {
            #pragma unroll
            for (int i = 0; i < 4; ++i) {
                int idx = tid + i * 256;
                if (idx < 832) ((unsigned int*)sG)[idx] = 0u;
            }
        }

        const unsigned short* krow = kb + (((size_t)(m*1024 + k0 + w*16 + lq)) << 6);
        short8 bk0 = *(const short8*)(krow + quad*8);
        short8 bk1 = *(const short8*)(krow + 32 + quad*8);
        f32x4 s4 = {0,0,0,0};
        s4 = __builtin_amdgcn_mfma_f32_16x16x32_bf16(aq0, bk0, s4, 0, 0, 0);
        s4 = __builtin_amdgcn_mfma_f32_16x16x32_bf16(aq1, bk1, s4, 0, 0, 0);

        float sc[4], mloc[4];
        const int kcol = k0 + w*16 + lq;
        #pragma unroll
        for (int i = 0; i < 4; ++i) {
            int row = quad*4 + i;
            int dist = (q0 + row) - kcol;
            int jd = dist < -128 ? 0 : (dist > 128 ? 256 : dist + 128);
            sc[i] = s4[i] + bf16f(sR[row][jd]);
            mloc[i] = sc[i];
        }
        #pragma unroll
        for (int off = 1; off < 16; off <<= 1)
            #pragma unroll
            for (int i = 0; i < 4; ++i)
                mloc[i] = fmaxf(mloc[i], __shfl_xor(mloc[i], off, 64));
        if (lq == 0) {
            #pragma unroll
            for (int i = 0; i < 4; ++i) sPartMax[w][quad*4 + i] = mloc[i];
        }
        __syncthreads();

        float mnew[4], alpha[4], e[4], psum[4];
        #pragma unroll
        for (int i = 0; i < 4; ++i) {
            int row = quad*4 + i;
            float ma = fmaxf(fmaxf(sPartMax[0][row], sPartMax[1][row]),
                             fmaxf(sPartMax[2][row], sPartMax[3][row]));
            mnew[i] = fmaxf(mrow[i], ma);
            alpha[i] = exp2f((mrow[i] - mnew[i]) * 1.44269504f);
            e[i] = exp2f((sc[i] - mnew[i]) * 1.44269504f);
            psum[i] = e[i];
        }
        #pragma unroll
        for (int off = 1; off < 16; off <<= 1)
            #pragma unroll
            for (int i = 0; i < 4; ++i)
                psum[i] += __shfl_xor(psum[i], off, 64);
        if (lq == 0) {
            #pragma unroll
            for (int i = 0; i < 4; ++i) sPartSum[w][quad*4 + i] = psum[i];
        }
        #pragma unroll
        for (int i = 0; i < 4; ++i) sP[quad*4 + i][w*16 + lq] = f2b(e[i]);
        __syncthreads();

        float sAll[4];
        #pragma unroll
        for (int i = 0; i < 4; ++i) {
            int row = quad*4 + i;
            sAll[i] = sPartSum[0][row] + sPartSum[1][row]
                    + sPartSum[2][row] + sPartSum[3][row];
            lrow[i] = lrow[i] * alpha[i] + sAll[i];
            mrow[i] = mnew[i];
            c1a[i] *= alpha[i];
            c2a[i] *= alpha[i];
        }

        {
            short8 ap0 = *(const short8*)&sP[lq][quad*8];
            short8 ap1 = *(const short8*)&sP[lq][32 + quad*8];
            const unsigned short* vrow = vt + (((size_t)(m*64 + w*16 + lq)) << 10) + k0;
            short8 bv0 = *(const short8*)(vrow + quad*8);
            short8 bv1 = *(const short8*)(vrow + 32 + quad*8);
            c1a = __builtin_amdgcn_mfma_f32_16x16x32_bf16(ap0, bv0, c1a, 0, 0, 0);
            c1a = __builtin_amdgcn_mfma_f32_16x16x32_bf16(ap1, bv1, c1a, 0, 0, 0);
        }

        if (clipped) {
            float re = fully_low ? relE0 : relE1;
            #pragma unroll
            for (int i = 0; i < 4; ++i) c2a[i] += sAll[i] * re;
        } else {
            if (pure_interior) {
                #pragma unroll
                for (int i2 = 0; i2 < 4; ++i2) {
                    int idx = tid + i2 * 256;
                    int q = idx >> 6, k2 = idx & 63;
                    sG[q][(q0 + q) - (k0 + k2) + 128 - jlo8] = sP[q][k2];
                }
            } else if (tid < 64) {
                int q = tid >> 2, part = tid & 3;
                float e0 = 0.0f, e256 = 0.0f;
                #pragma unroll 1
                for (int kk = part*16; kk < part*16 + 16; ++kk) {
                    int dist = (q0 + q) - (k0 + kk);
                    if (dist <= -128)      e0   += bf16f(sP[q][kk]);
                    else if (dist >= 128)  e256 += bf16f(sP[q][kk]);
                    else                   sG[q][dist + 128 - jlo8] = sP[q][kk];
                }
                e0   += __shfl_xor(e0, 1, 64);   e0   += __shfl_xor(e0, 2, 64);
                e256 += __shfl_xor(e256, 1, 64); e256 += __shfl_xor(e256, 2, 64);
                if (part == 0) {
                    if (jminU < 0)   sG[q][0]           = f2b(e0);
                    if (jmaxU > 256) sG[q][256 - jlo8]  = f2b(e256);
                }
            }
            __syncthreads();
            short8 ag0 = *(const short8*)&sG[lq][quad*8];
            short8 ag1 = *(const short8*)&sG[lq][32 + quad*8];
            short8 ag2 = *(const short8*)&sG[lq][64 + quad*8];
            const unsigned short* rrow = relvT + (size_t)(w*16 + lq) * 264 + jlo8;
            short8 br0 = *(const short8*)(rrow + quad*8);
            short8 br1 = *(const short8*)(rrow + 32 + quad*8);
            short8 br2 = *(const short8*)(rrow + 64 + quad*8);
            c2a = __builtin_amdgcn_mfma_f32_16x16x32_bf16(ag0, br0, c2a, 0, 0, 0);
            c2a = __builtin_amdgcn_mfma_f32_16x16x32_bf16(ag1, br1, c2a, 0, 0, 0);
            c2a = __builtin_amdgcn_mfma_f32_16x16x32_bf16(ag2, br2, c2a, 0, 0, 0);
            __syncthreads();
        }
    }

    const int b1 = m >> 4,  h1 = m & 15;
    const int b2 = m2 >> 4, h2 = m2 & 15;
    #pragma unroll
    for (int i = 0; i < 4; ++i) {
        int row = quad*4 + i;
        float inv = 1.0f / lrow[i];
        int col = w*16 + lq;
        c1[(size_t)(b1*1024 + q0 + row) * 1024 + h1*64 + col] = c1a[i] * inv;
        c2[(size_t)(b2*1024 + q0 + row) * 1024 + h2*64 + col] = c2a[i] * inv;
    }
}

// ---------------------------------------------------------------------------
// K3: out = (c1+c2) @ Wo^T + bo via split-bf16 MFMA (A split on the fly).
// ---------------------------------------------------------------------------
__global__ __launch_bounds__(256) void k_gemm_o(
    const float* __restrict__ c1, const float* __restrict__ c2,
    const unsigned short* __restrict__ woh, const unsigned short* __restrict__ wol,
    const float* __restrict__ bo, float* __restrict__ outp)
{
    __shared__ __align__(16) unsigned short sAh[128][48];
    __shared__ __align__(16) unsigned short sAl[128][48];
    __shared__ __align__(16) unsigned short sBh[128][48];
    __shared__ __align__(16) unsigned short sBl[128][48];
    const int tid = threadIdx.x;
    const int eb = blockIdx.x * 128, nb = blockIdx.y * 128;
    const int w = tid >> 6, lane = tid & 63, lq = lane & 15, quad = lane >> 4;
    const int wr = w >> 1, wc = w & 1;
    const int srow = tid >> 2, sc8 = (tid & 3) * 8;

    f32x4 acc[4][4];
    #pragma unroll
    for (int i = 0; i < 4; ++i)
        #pragma unroll
        for (int j = 0; j < 4; ++j) acc[i][j] = (f32x4){0,0,0,0};

    for (int k0 = 0; k0 < 1024; k0 += 32) {
        float av[2][8];
        #pragma unroll
        for (int r2 = 0; r2 < 2; ++r2) {
            size_t off = (size_t)(nb + srow + r2*64) * 1024 + k0 + sc8;
            float4 x0 = *(const float4*)(c1 + off);
            float4 x1 = *(const float4*)(c1 + off + 4);
            float4 y0 = *(const float4*)(c2 + off);
            float4 y1 = *(const float4*)(c2 + off + 4);
            av[r2][0] = x0.x + y0.x; av[r2][1] = x0.y + y0.y;
            av[r2][2] = x0.z + y0.z; av[r2][3] = x0.w + y0.w;
            av[r2][4] = x1.x + y1.x; av[r2][5] = x1.y + y1.y;
            av[r2][6] = x1.z + y1.z; av[r2][7] = x1.w + y1.w;
        }
        uint4 b0h = *(const uint4*)(woh + (size_t)(eb + srow) * 1024 + k0 + sc8);
        uint4 b1h = *(const uint4*)(woh + (size_t)(eb + srow + 64) * 1024 + k0 + sc8);
        uint4 b0l = *(const uint4*)(wol + (size_t)(eb + srow) * 1024 + k0 + sc8);
        uint4 b1l = *(const uint4*)(wol + (size_t)(eb + srow + 64) * 1024 + k0 + sc8);
        __syncthreads();
        #pragma unroll
        for (int r2 = 0; r2 < 2; ++r2) {
            unsigned short hh8[8], ll8[8];
            #pragma unroll
            for (int j = 0; j < 8; ++j) {
                hh8[j] = f2b(av[r2][j]);
                ll8[j] = f2b(av[r2][j] - bf16f(hh8[j]));
            }
            *(uint4*)&sAh[srow + r2*64][sc8] = *(const uint4*)hh8;
            *(uint4*)&sAl[srow + r2*64][sc8] = *(const uint4*)ll8;
        }
        *(uint4*)&sBh[srow][sc8] = b0h;  *(uint4*)&sBh[srow + 64][sc8] = b1h;
        *(uint4*)&sBl[srow][sc8] = b0l;  *(uint4*)&sBl[srow + 64][sc8] = b1l;
        __syncthreads();

        short8 ah[4], al[4], bhf[4], blf[4];
        #pragma unroll
        for (int t = 0; t < 4; ++t) {
            ah[t]  = *(const short8*)&sAh[wr*64 + t*16 + lq][quad*8];
            al[t]  = *(const short8*)&sAl[wr*64 + t*16 + lq][quad*8];
            bhf[t] = *(const short8*)&sBh[wc*64 + t*16 + lq][quad*8];
            blf[t] = *(const short8*)&sBl[wc*64 + t*16 + lq][quad*8];
        }
        #pragma unroll
        for (int ti = 0; ti < 4; ++ti)
            #pragma unroll
            for (int tj = 0; tj < 4; ++tj) {
                acc[ti][tj] = __builtin_amdgcn_mfma_f32_16x16x32_bf16(ah[ti], bhf[tj], acc[ti][tj], 0, 0, 0);
                acc[ti][tj] = __builtin_amdgcn_mfma_f32_16x16x32_bf16(al[ti], bhf[tj], acc[ti][tj], 0, 0, 0);
                acc[ti][tj] = __builtin_amdgcn_mfma_f32_16x16x32_bf16(ah[ti], blf[tj], acc[ti][tj], 0, 0, 0);
            }
    }

    #pragma unroll
    for (int tj = 0; tj < 4; ++tj) {
        int e = eb + wc*64 + tj*16 + lq;
        float bb = bo[e];
        #pragma unroll
        for (int ti = 0; ti < 4; ++ti) {
            #pragma unroll
            for (int i = 0; i < 4; ++i) {
                int n = nb + wr*64 + ti*16 + quad*4 + i;
                outp[(size_t)n * 1024 + e] = acc[ti][tj][i] + bb;
            }
        }
    }
}

// ---------------------------------------------------------------------------
extern "C" void kernel_launch(void* const* d_in, const int* in_sizes, int n_in,
                              void* d_out, int out_size, void* d_ws, size_t ws_size,
                              hipStream_t stream) {
    const float* hs   = (const float*)d_in[0];
    const float* Wq   = (const float*)d_in[1];
    const float* bq   = (const float*)d_in[2];
    const float* Wk   = (const float*)d_in[3];
    const float* bk   = (const float*)d_in[4];
    const float* Wv   = (const float*)d_in[5];
    const float* bv   = (const float*)d_in[6];
    const float* Wo   = (const float*)d_in[7];
    const float* bo   = (const float*)d_in[8];
    const float* relk = (const float*)d_in[9];
    const float* relv = (const float*)d_in[10];
    float* out = (float*)d_out;

    // Workspace (shorts): qb/kb/vt 3x4M @0/4M/8M; relkB @12582912 (17408);
    // relvT @12600320 (17040); c1/c2 fp32 @ short idx 12617360 (4M floats ea);
    // hh/hl @29394576/33588880; W hi/lo pairs after.  Total ~92 MB (ws>=280MB).
    unsigned short* wsu = (unsigned short*)d_ws;
    unsigned short* qbp   = wsu;
    unsigned short* kbp   = wsu + 4194304;
    unsigned short* vtp   = wsu + 8388608;
    unsigned short* relkB = wsu + 12582912;
    unsigned short* relvT = wsu + 12600320;
    float* c1 = (float*)(wsu + 12617360);
    float* c2 = c1 + 4194304;
    unsigned short* hh  = wsu + 29394576;
    unsigned short* hl  = hh + 4194304;
    unsigned short* wqh = hl + 4194304;
    unsigned short* wql = wqh + 1048576;
    unsigned short* wkh = wql + 1048576;
    unsigned short* wkl = wkh + 1048576;
    unsigned short* wvh = wkl + 1048576;
    unsigned short* wvl = wvh + 1048576;
    unsigned short* woh = wvl + 1048576;
    unsigned short* wol = woh + 1048576;

    k_split<<<dim3(512), 256, 0, stream>>>(hs, hh, hl, 1048576);
    k_split<<<dim3(128), 256, 0, stream>>>(Wq, wqh, wql, 262144);
    k_split<<<dim3(128), 256, 0, stream>>>(Wk, wkh, wkl, 262144);
    k_split<<<dim3(128), 256, 0, stream>>>(Wv, wvh, wvl, 262144);
    k_split<<<dim3(128), 256, 0, stream>>>(Wo, woh, wol, 262144);
    k_rel  <<<dim3(1),   256, 0, stream>>>(relk, relv, relkB, relvT);
    k_gemm_qkv<<<dim3(8, 32, 3), 256, 0, stream>>>(hh, hl, wqh, wql, wkh, wkl,
                                                   wvh, wvl, bq, bk, bv,
                                                   qbp, kbp, vtp);
    k_fused<<<dim3(64, 64), 256, 0, stream>>>(qbp, kbp, vtp, relkB, relvT, relv, c1, c2);
    k_gemm_o<<<dim3(8, 32), 256, 0, stream>>>(c1, c2, woh, wol, bo, out);
}

// Round 9
// 483.330 us; speedup vs baseline: 27.7259x; 1.1485x over previous
//
#include <hip/hip_runtime.h>
#include <hip/hip_bf16.h>

// B=4, T=1024, E=1024, H=16, D=64, P=257.  Slot s = b*16+h (64 slots).
// Quirk: score slot m uses rel-K of slot pm=(m&15)*4+(m>>4); attn of slot m
// feeds w2 output of slot m2=(m&3)*16+(m>>2).
// R9: k_fused drops online-softmax. Norm bound: |score| <= |q/8||k|+|R| < 4
// (<< fp32 exp limit 88), so exp with fixed m=0 is safe. lrow and the
// clipped-tile edge sums (S_low*relv[0]+S_high*relv[256]) are per-lane
// accumulators reduced ONCE at the end. sP double-buffered: clipped tiles =
// 1 barrier, no shuffles.  Prep work merged into one kernel (4 dispatches).

typedef __attribute__((ext_vector_type(8))) short short8;
typedef __attribute__((ext_vector_type(4))) float f32x4;

__device__ __forceinline__ float bf16f(unsigned int u) {
    union { unsigned int i; float f; } v; v.i = u << 16; return v.f;
}
__device__ __forceinline__ unsigned short f2b(float x) {
    __hip_bfloat16 h = __float2bfloat16(x);
    return *reinterpret_cast<unsigned short*>(&h);
}

// ---------------------------------------------------------------------------
// K0: prep.  z=0..4: split fp32 -> (hi,lo) bf16 for hs/Wq/Wk/Wv/Wo.
// z=5 (block 0 only): relkB bf16 [272][64] (rows>=257 zero) and
// relvT bf16 relv^T [64][264] (cols>=257 zero).
// ---------------------------------------------------------------------------
__global__ __launch_bounds__(256) void k_prep(
    const float* __restrict__ hs, const float* __restrict__ Wq,
    const float* __restrict__ Wk, const float* __restrict__ Wv,
    const float* __restrict__ Wo, const float* __restrict__ relk,
    const float* __restrict__ relv,
    unsigned short* __restrict__ hh, unsigned short* __restrict__ hl,
    unsigned short* __restrict__ wqh, unsigned short* __restrict__ wql,
    unsigned short* __restrict__ wkh, unsigned short* __restrict__ wkl,
    unsigned short* __restrict__ wvh, unsigned short* __restrict__ wvl,
    unsigned short* __restrict__ woh, unsigned short* __restrict__ wol,
    unsigned short* __restrict__ relkB, unsigned short* __restrict__ relvT)
{
    const int z = blockIdx.y;
    const int tid = threadIdx.x;
    if (z < 5) {
        const float* src = (z == 0) ? hs : (z == 1) ? Wq : (z == 2) ? Wk
                         : (z == 3) ? Wv : Wo;
        unsigned short* hi = (z == 0) ? hh : (z == 1) ? wqh : (z == 2) ? wkh
                           : (z == 3) ? wvh : woh;
        unsigned short* lo = (z == 0) ? hl : (z == 1) ? wql : (z == 2) ? wkl
                           : (z == 3) ? wvl : wol;
        const int n4 = (z == 0) ? 1048576 : 262144;
        const int stride = gridDim.x * 256;
        for (int i = blockIdx.x * 256 + tid; i < n4; i += stride) {
            float4 x = *(const float4*)(src + i*4);
            unsigned short h[4], l[4];
            float xs[4] = {x.x, x.y, x.z, x.w};
            #pragma unroll
            for (int j = 0; j < 4; ++j) {
                h[j] = f2b(xs[j]);
                l[j] = f2b(xs[j] - bf16f(h[j]));
            }
            *(ushort4*)(hi + i*4) = make_ushort4(h[0], h[1], h[2], h[3]);
            *(ushort4*)(lo + i*4) = make_ushort4(l[0], l[1], l[2], l[3]);
        }
    } else if (blockIdx.x == 0) {
        for (int i = tid; i < 272*64; i += 256) {
            int j = i >> 6;
            relkB[i] = (j < 257) ? f2b(relk[i]) : (unsigned short)0;
        }
        int d = tid >> 2, grp = tid & 3;
        for (int jj = 0; jj < 66; ++jj) {
            int j = grp*66 + jj;
            if (j < 264)
                relvT[d*264 + j] = (j < 257) ? f2b(relv[j*64 + d]) : (unsigned short)0;
        }
    }
}

// ---------------------------------------------------------------------------
// K1: QKV projection via split-bf16 MFMA (unchanged from R8).
// ---------------------------------------------------------------------------
__global__ __launch_bounds__(256) void k_gemm_qkv(
    const unsigned short* __restrict__ hh, const unsigned short* __restrict__ hl,
    const unsigned short* __restrict__ wqh, const unsigned short* __restrict__ wql,
    const unsigned short* __restrict__ wkh, const unsigned short* __restrict__ wkl,
    const unsigned short* __restrict__ wvh, const unsigned short* __restrict__ wvl,
    const float* __restrict__ bq, const float* __restrict__ bk,
    const float* __restrict__ bv,
    unsigned short* __restrict__ qb, unsigned short* __restrict__ kb,
    unsigned short* __restrict__ vt)
{
    __shared__ __align__(16) unsigned short sAh[128][48];
    __shared__ __align__(16) unsigned short sAl[128][48];
    __shared__ __align__(16) unsigned short sBh[128][48];
    __shared__ __align__(16) unsigned short sBl[128][48];
    const int tid = threadIdx.x;
    const int eb = blockIdx.x * 128, nb = blockIdx.y * 128, z = blockIdx.z;
    const unsigned short* Bh = (z == 0) ? wqh : (z == 1) ? wkh : wvh;
    const unsigned short* Bl = (z == 0) ? wql : (z == 1) ? wkl : wvl;
    const float* bias = (z == 0) ? bq : (z == 1) ? bk : bv;
    const float scale = (z == 0) ? 0.125f : 1.0f;
    const int w = tid >> 6, lane = tid & 63, lq = lane & 15, quad = lane >> 4;
    const int wr = w >> 1, wc = w & 1;
    const int srow = tid >> 2, sc8 = (tid & 3) * 8;

    f32x4 acc[4][4];
    #pragma unroll
    for (int i = 0; i < 4; ++i)
        #pragma unroll
        for (int j = 0; j < 4; ++j) acc[i][j] = (f32x4){0,0,0,0};

    for (int k0 = 0; k0 < 1024; k0 += 32) {
        uint4 a0h = *(const uint4*)(hh + (size_t)(nb + srow) * 1024 + k0 + sc8);
        uint4 a1h = *(const uint4*)(hh + (size_t)(nb + srow + 64) * 1024 + k0 + sc8);
        uint4 a0l = *(const uint4*)(hl + (size_t)(nb + srow) * 1024 + k0 + sc8);
        uint4 a1l = *(const uint4*)(hl + (size_t)(nb + srow + 64) * 1024 + k0 + sc8);
        uint4 b0h = *(const uint4*)(Bh + (size_t)(eb + srow) * 1024 + k0 + sc8);
        uint4 b1h = *(const uint4*)(Bh + (size_t)(eb + srow + 64) * 1024 + k0 + sc8);
        uint4 b0l = *(const uint4*)(Bl + (size_t)(eb + srow) * 1024 + k0 + sc8);
        uint4 b1l = *(const uint4*)(Bl + (size_t)(eb + srow + 64) * 1024 + k0 + sc8);
        __syncthreads();
        *(uint4*)&sAh[srow][sc8] = a0h;  *(uint4*)&sAh[srow + 64][sc8] = a1h;
        *(uint4*)&sAl[srow][sc8] = a0l;  *(uint4*)&sAl[srow + 64][sc8] = a1l;
        *(uint4*)&sBh[srow][sc8] = b0h;  *(uint4*)&sBh[srow + 64][sc8] = b1h;
        *(uint4*)&sBl[srow][sc8] = b0l;  *(uint4*)&sBl[srow + 64][sc8] = b1l;
        __syncthreads();

        short8 ah[4], al[4], bhf[4], blf[4];
        #pragma unroll
        for (int t = 0; t < 4; ++t) {
            ah[t]  = *(const short8*)&sAh[wr*64 + t*16 + lq][quad*8];
            al[t]  = *(const short8*)&sAl[wr*64 + t*16 + lq][quad*8];
            bhf[t] = *(const short8*)&sBh[wc*64 + t*16 + lq][quad*8];
            blf[t] = *(const short8*)&sBl[wc*64 + t*16 + lq][quad*8];
        }
        #pragma unroll
        for (int ti = 0; ti < 4; ++ti)
            #pragma unroll
            for (int tj = 0; tj < 4; ++tj) {
                acc[ti][tj] = __builtin_amdgcn_mfma_f32_16x16x32_bf16(ah[ti], bhf[tj], acc[ti][tj], 0, 0, 0);
                acc[ti][tj] = __builtin_amdgcn_mfma_f32_16x16x32_bf16(al[ti], bhf[tj], acc[ti][tj], 0, 0, 0);
                acc[ti][tj] = __builtin_amdgcn_mfma_f32_16x16x32_bf16(ah[ti], blf[tj], acc[ti][tj], 0, 0, 0);
            }
    }

    #pragma unroll
    for (int tj = 0; tj < 4; ++tj) {
        int e = eb + wc*64 + tj*16 + lq;
        float bb = bias[e];
        int h = e >> 6, d = e & 63;
        #pragma unroll
        for (int ti = 0; ti < 4; ++ti) {
            #pragma unroll
            for (int i = 0; i < 4; ++i) {
                int n = nb + wr*64 + ti*16 + quad*4 + i;
                int bidx = n >> 10, t = n & 1023;
                int s = bidx*16 + h;
                float val = (acc[ti][tj][i] + bb) * scale;
                if (z == 2)
                    vt[(((size_t)(s*64 + d)) << 10) + t] = f2b(val);
                else if (z == 0)
                    qb[(((size_t)(s*1024 + t)) << 6) + d] = f2b(val);
                else
                    kb[(((size_t)(s*1024 + t)) << 6) + d] = f2b(val);
            }
        }
    }
}

// ---------------------------------------------------------------------------
// K2: MFMA flash attention, max-free softmax (m=0 fixed; see header bound).
// ---------------------------------------------------------------------------
__global__ __launch_bounds__(256) void k_fused(
    const unsigned short* __restrict__ qb, const unsigned short* __restrict__ kb,
    const unsigned short* __restrict__ vt, const unsigned short* __restrict__ relkB,
    const unsigned short* __restrict__ relvT, const float* __restrict__ relv,
    float* __restrict__ c1, float* __restrict__ c2)
{
    __shared__ __align__(16) unsigned short sP[2][16][72];  // double-buffered
    __shared__ __align__(16) unsigned short sG[16][104];
    __shared__ unsigned short sR[16][273];
    __shared__ float sRed[4][3][16];

    const int tid = threadIdx.x;
    const int m  = blockIdx.y;
    const int q0 = blockIdx.x * 16;
    const int pm = (m & 15) * 4 + (m >> 4);
    const int m2 = (m & 3) * 16 + (m >> 2);
    const int w    = tid >> 6;
    const int lane = tid & 63;
    const int lq   = lane & 15;
    const int quad = lane >> 4;

    // ---- Phase A: R table via MFMA ----
    {
        const unsigned short* qpm = qb + (((size_t)(pm*1024 + q0 + lq)) << 6);
        short8 apm0 = *(const short8*)(qpm + quad*8);
        short8 apm1 = *(const short8*)(qpm + 32 + quad*8);
        for (int jt = w; jt < 17; jt += 4) {
            const unsigned short* rkb = relkB + (size_t)(jt*16 + lq) * 64;
            short8 b0 = *(const short8*)(rkb + quad*8);
            short8 b1 = *(const short8*)(rkb + 32 + quad*8);
            f32x4 cr = {0,0,0,0};
            cr = __builtin_amdgcn_mfma_f32_16x16x32_bf16(apm0, b0, cr, 0, 0, 0);
            cr = __builtin_amdgcn_mfma_f32_16x16x32_bf16(apm1, b1, cr, 0, 0, 0);
            #pragma unroll
            for (int i = 0; i < 4; ++i) sR[quad*4 + i][jt*16 + lq] = f2b(cr[i]);
        }
    }
    __syncthreads();

    const unsigned short* qm = qb + (((size_t)(m*1024 + q0 + lq)) << 6);
    const short8 aq0 = *(const short8*)(qm + quad*8);
    const short8 aq1 = *(const short8*)(qm + 32 + quad*8);
    const float relE0 = relv[w*16 + lq];
    const float relE1 = relv[256*64 + w*16 + lq];

    float lsum[4] = {0,0,0,0}, slow[4] = {0,0,0,0}, shigh[4] = {0,0,0,0};
    f32x4 c1a = {0,0,0,0}, c2a = {0,0,0,0};

    #pragma unroll 1
    for (int kt = 0; kt < 16; ++kt) {
        const int k0 = kt * 64;
        const int buf = kt & 1;
        const int jminU = q0 - k0 - 63 + 128;
        const int jmaxU = q0 - k0 + 15 + 128;
        const bool fully_low  = (jmaxU <= 0);
        const bool fully_high = (jminU >= 256);
        const bool clipped = fully_low || fully_high;
        const bool pure_interior = (jminU >= 0) && (jmaxU <= 256);
        const int jlo8 = (jminU < 0) ? 0 : (jminU & ~7);

        // ---- QK^T MFMA ----
        const unsigned short* krow = kb + (((size_t)(m*1024 + k0 + w*16 + lq)) << 6);
        short8 bk0 = *(const short8*)(krow + quad*8);
        short8 bk1 = *(const short8*)(krow + 32 + quad*8);
        f32x4 s4 = {0,0,0,0};
        s4 = __builtin_amdgcn_mfma_f32_16x16x32_bf16(aq0, bk0, s4, 0, 0, 0);
        s4 = __builtin_amdgcn_mfma_f32_16x16x32_bf16(aq1, bk1, s4, 0, 0, 0);

        // exp (no max shift), accumulate lsum / edge sums per-lane
        const int kcol = k0 + w*16 + lq;
        float e[4];
        #pragma unroll
        for (int i = 0; i < 4; ++i) {
            int row = quad*4 + i;
            int dist = (q0 + row) - kcol;
            int jd = dist < -128 ? 0 : (dist > 128 ? 256 : dist + 128);
            e[i] = exp2f((s4[i] + bf16f(sR[row][jd])) * 1.44269504f);
            lsum[i] += e[i];
            sP[buf][row][w*16 + lq] = f2b(e[i]);
        }
        if (clipped) {
            if (fully_low) {
                #pragma unroll
                for (int i = 0; i < 4; ++i) slow[i] += e[i];
            } else {
                #pragma unroll
                for (int i = 0; i < 4; ++i) shigh[i] += e[i];
            }
        } else {
            #pragma unroll
            for (int i = 0; i < 4; ++i) {
                int idx = tid + i * 256;
                if (idx < 832) ((unsigned int*)sG)[idx] = 0u;
            }
        }
        __syncthreads();   // A: sP[buf] (+ sG zero) visible

        // ---- P·V MFMA ----
        {
            short8 ap0 = *(const short8*)&sP[buf][lq][quad*8];
            short8 ap1 = *(const short8*)&sP[buf][lq][32 + quad*8];
            const unsigned short* vrow = vt + (((size_t)(m*64 + w*16 + lq)) << 10) + k0;
            short8 bv0 = *(const short8*)(vrow + quad*8);
            short8 bv1 = *(const short8*)(vrow + 32 + quad*8);
            c1a = __builtin_amdgcn_mfma_f32_16x16x32_bf16(ap0, bv0, c1a, 0, 0, 0);
            c1a = __builtin_amdgcn_mfma_f32_16x16x32_bf16(ap1, bv1, c1a, 0, 0, 0);
        }

        if (!clipped) {
            if (pure_interior) {
                #pragma unroll
                for (int i2 = 0; i2 < 4; ++i2) {
                    int idx = tid + i2 * 256;
                    int q = idx >> 6, k2 = idx & 63;
                    sG[q][(q0 + q) - (k0 + k2) + 128 - jlo8] = sP[buf][q][k2];
                }
            } else if (tid < 64) {
                int q = tid >> 2, part = tid & 3;
                float e0 = 0.0f, e256 = 0.0f;
                #pragma unroll 1
                for (int kk = part*16; kk < part*16 + 16; ++kk) {
                    int dist = (q0 + q) - (k0 + kk);
                    if (dist <= -128)      e0   += bf16f(sP[buf][q][kk]);
                    else if (dist >= 128)  e256 += bf16f(sP[buf][q][kk]);
                    else                   sG[q][dist + 128 - jlo8] = sP[buf][q][kk];
                }
                e0   += __shfl_xor(e0, 1, 64);   e0   += __shfl_xor(e0, 2, 64);
                e256 += __shfl_xor(e256, 1, 64); e256 += __shfl_xor(e256, 2, 64);
                if (part == 0) {
                    if (jminU < 0)   sG[q][0]           = f2b(e0);
                    if (jmaxU > 256) sG[q][256 - jlo8]  = f2b(e256);
                }
            }
            __syncthreads();   // B: sG ready
            short8 ag0 = *(const short8*)&sG[lq][quad*8];
            short8 ag1 = *(const short8*)&sG[lq][32 + quad*8];
            short8 ag2 = *(const short8*)&sG[lq][64 + quad*8];
            const unsigned short* rrow = relvT + (size_t)(w*16 + lq) * 264 + jlo8;
            short8 br0 = *(const short8*)(rrow + quad*8);
            short8 br1 = *(const short8*)(rrow + 32 + quad*8);
            short8 br2 = *(const short8*)(rrow + 64 + quad*8);
            c2a = __builtin_amdgcn_mfma_f32_16x16x32_bf16(ag0, br0, c2a, 0, 0, 0);
            c2a = __builtin_amdgcn_mfma_f32_16x16x32_bf16(ag1, br1, c2a, 0, 0, 0);
            c2a = __builtin_amdgcn_mfma_f32_16x16x32_bf16(ag2, br2, c2a, 0, 0, 0);
            __syncthreads();   // C: protect sG before next tile's zero
        }
    }

    // ---- final reductions: 16-lane shuffle then cross-wave LDS ----
    #pragma unroll
    for (int off = 1; off < 16; off <<= 1) {
        #pragma unroll
        for (int i = 0; i < 4; ++i) {
            lsum[i]  += __shfl_xor(lsum[i],  off, 64);
            slow[i]  += __shfl_xor(slow[i],  off, 64);
            shigh[i] += __shfl_xor(shigh[i], off, 64);
        }
    }
    if (lq == 0) {
        #pragma unroll
        for (int i = 0; i < 4; ++i) {
            sRed[w][0][quad*4 + i] = lsum[i];
            sRed[w][1][quad*4 + i] = slow[i];
            sRed[w][2][quad*4 + i] = shigh[i];
        }
    }
    __syncthreads();

    const int b1 = m >> 4,  h1 = m & 15;
    const int b2 = m2 >> 4, h2 = m2 & 15;
    #pragma unroll
    for (int i = 0; i < 4; ++i) {
        int row = quad*4 + i;
        float lt = sRed[0][0][row] + sRed[1][0][row] + sRed[2][0][row] + sRed[3][0][row];
        float sl = sRed[0][1][row] + sRed[1][1][row] + sRed[2][1][row] + sRed[3][1][row];
        float sh = sRed[0][2][row] + sRed[1][2][row] + sRed[2][2][row] + sRed[3][2][row];
        float c2v = c2a[i] + sl * relE0 + sh * relE1;
        float inv = 1.0f / lt;
        int col = w*16 + lq;
        c1[(size_t)(b1*1024 + q0 + row) * 1024 + h1*64 + col] = c1a[i] * inv;
        c2[(size_t)(b2*1024 + q0 + row) * 1024 + h2*64 + col] = c2v * inv;
    }
}

// ---------------------------------------------------------------------------
// K3: out = (c1+c2) @ Wo^T + bo via split-bf16 MFMA (unchanged from R8).
// ---------------------------------------------------------------------------
__global__ __launch_bounds__(256) void k_gemm_o(
    const float* __restrict__ c1, const float* __restrict__ c2,
    const unsigned short* __restrict__ woh, const unsigned short* __restrict__ wol,
    const float* __restrict__ bo, float* __restrict__ outp)
{
    __shared__ __align__(16) unsigned short sAh[128][48];
    __shared__ __align__(16) unsigned short sAl[128][48];
    __shared__ __align__(16) unsigned short sBh[128][48];
    __shared__ __align__(16) unsigned short sBl[128][48];
    const int tid = threadIdx.x;
    const int eb = blockIdx.x * 128, nb = blockIdx.y * 128;
    const int w = tid >> 6, lane = tid & 63, lq = lane & 15, quad = lane >> 4;
    const int wr = w >> 1, wc = w & 1;
    const int srow = tid >> 2, sc8 = (tid & 3) * 8;

    f32x4 acc[4][4];
    #pragma unroll
    for (int i = 0; i < 4; ++i)
        #pragma unroll
        for (int j = 0; j < 4; ++j) acc[i][j] = (f32x4){0,0,0,0};

    for (int k0 = 0; k0 < 1024; k0 += 32) {
        float av[2][8];
        #pragma unroll
        for (int r2 = 0; r2 < 2; ++r2) {
            size_t off = (size_t)(nb + srow + r2*64) * 1024 + k0 + sc8;
            float4 x0 = *(const float4*)(c1 + off);
            float4 x1 = *(const float4*)(c1 + off + 4);
            float4 y0 = *(const float4*)(c2 + off);
            float4 y1 = *(const float4*)(c2 + off + 4);
            av[r2][0] = x0.x + y0.x; av[r2][1] = x0.y + y0.y;
            av[r2][2] = x0.z + y0.z; av[r2][3] = x0.w + y0.w;
            av[r2][4] = x1.x + y1.x; av[r2][5] = x1.y + y1.y;
            av[r2][6] = x1.z + y1.z; av[r2][7] = x1.w + y1.w;
        }
        uint4 b0h = *(const uint4*)(woh + (size_t)(eb + srow) * 1024 + k0 + sc8);
        uint4 b1h = *(const uint4*)(woh + (size_t)(eb + srow + 64) * 1024 + k0 + sc8);
        uint4 b0l = *(const uint4*)(wol + (size_t)(eb + srow) * 1024 + k0 + sc8);
        uint4 b1l = *(const uint4*)(wol + (size_t)(eb + srow + 64) * 1024 + k0 + sc8);
        __syncthreads();
        #pragma unroll
        for (int r2 = 0; r2 < 2; ++r2) {
            unsigned short hh8[8], ll8[8];
            #pragma unroll
            for (int j = 0; j < 8; ++j) {
                hh8[j] = f2b(av[r2][j]);
                ll8[j] = f2b(av[r2][j] - bf16f(hh8[j]));
            }
            *(uint4*)&sAh[srow + r2*64][sc8] = *(const uint4*)hh8;
            *(uint4*)&sAl[srow + r2*64][sc8] = *(const uint4*)ll8;
        }
        *(uint4*)&sBh[srow][sc8] = b0h;  *(uint4*)&sBh[srow + 64][sc8] = b1h;
        *(uint4*)&sBl[srow][sc8] = b0l;  *(uint4*)&sBl[srow + 64][sc8] = b1l;
        __syncthreads();

        short8 ah[4], al[4], bhf[4], blf[4];
        #pragma unroll
        for (int t = 0; t < 4; ++t) {
            ah[t]  = *(const short8*)&sAh[wr*64 + t*16 + lq][quad*8];
            al[t]  = *(const short8*)&sAl[wr*64 + t*16 + lq][quad*8];
            bhf[t] = *(const short8*)&sBh[wc*64 + t*16 + lq][quad*8];
            blf[t] = *(const short8*)&sBl[wc*64 + t*16 + lq][quad*8];
        }
        #pragma unroll
        for (int ti = 0; ti < 4; ++ti)
            #pragma unroll
            for (int tj = 0; tj < 4; ++tj) {
                acc[ti][tj] = __builtin_amdgcn_mfma_f32_16x16x32_bf16(ah[ti], bhf[tj], acc[ti][tj], 0, 0, 0);
                acc[ti][tj] = __builtin_amdgcn_mfma_f32_16x16x32_bf16(al[ti], bhf[tj], acc[ti][tj], 0, 0, 0);
                acc[ti][tj] = __builtin_amdgcn_mfma_f32_16x16x32_bf16(ah[ti], blf[tj], acc[ti][tj], 0, 0, 0);
            }
    }

    #pragma unroll
    for (int tj = 0; tj < 4; ++tj) {
        int e = eb + wc*64 + tj*16 + lq;
        float bb = bo[e];
        #pragma unroll
        for (int ti = 0; ti < 4; ++ti) {
            #pragma unroll
            for (int i = 0; i < 4; ++i) {
                int n = nb + wr*64 + ti*16 + quad*4 + i;
                outp[(size_t)n * 1024 + e] = acc[ti][tj][i] + bb;
            }
        }
    }
}

// ---------------------------------------------------------------------------
extern "C" void kernel_launch(void* const* d_in, const int* in_sizes, int n_in,
                              void* d_out, int out_size, void* d_ws, size_t ws_size,
                              hipStream_t stream) {
    const float* hs   = (const float*)d_in[0];
    const float* Wq   = (const float*)d_in[1];
    const float* bq   = (const float*)d_in[2];
    const float* Wk   = (const float*)d_in[3];
    const float* bk   = (const float*)d_in[4];
    const float* Wv   = (const float*)d_in[5];
    const float* bv   = (const float*)d_in[6];
    const float* Wo   = (const float*)d_in[7];
    const float* bo   = (const float*)d_in[8];
    const float* relk = (const float*)d_in[9];
    const float* relv = (const float*)d_in[10];
    float* out = (float*)d_out;

    unsigned short* wsu = (unsigned short*)d_ws;
    unsigned short* qbp   = wsu;
    unsigned short* kbp   = wsu + 4194304;
    unsigned short* vtp   = wsu + 8388608;
    unsigned short* relkB = wsu + 12582912;
    unsigned short* relvT = wsu + 12600320;
    float* c1 = (float*)(wsu + 12617360);
    float* c2 = c1 + 4194304;
    unsigned short* hh  = wsu + 29394576;
    unsigned short* hl  = hh + 4194304;
    unsigned short* wqh = hl + 4194304;
    unsigned short* wql = wqh + 1048576;
    unsigned short* wkh = wql + 1048576;
    unsigned short* wkl = wkh + 1048576;
    unsigned short* wvh = wkl + 1048576;
    unsigned short* wvl = wvh + 1048576;
    unsigned short* woh = wvl + 1048576;
    unsigned short* wol = woh + 1048576;

    k_prep<<<dim3(512, 6), 256, 0, stream>>>(hs, Wq, Wk, Wv, Wo, relk, relv,
                                             hh, hl, wqh, wql, wkh, wkl,
                                             wvh, wvl, woh, wol, relkB, relvT);
    k_gemm_qkv<<<dim3(8, 32, 3), 256, 0, stream>>>(hh, hl, wqh, wql, wkh, wkl,
                                                   wvh, wvl, bq, bk, bv,
                                                   qbp, kbp, vtp);
    k_fused<<<dim3(64, 64), 256, 0, stream>>>(qbp, kbp, vtp, relkB, relvT, relv, c1, c2);
    k_gemm_o<<<dim3(8, 32), 256, 0, stream>>>(c1, c2, woh, wol, bo, out);
}

// Round 11
// 433.362 us; speedup vs baseline: 30.9228x; 1.1153x over previous
//
#include <hip/hip_runtime.h>
#include <hip/hip_bf16.h>

// B=4, T=1024, E=1024, H=16, D=64, P=257.  Slot s = b*16+h (64 slots).
// Quirk: score slot m uses rel-K of slot pm=(m&15)*4+(m>>4); attn of slot m
// feeds w2 output of slot m2=(m&3)*16+(m>>2).
// R11 = R10 + fixes: (1) sG zero loop covers BOTH sub-buffers (1664 uints;
// R10 zeroed only 832 -> sG[1] was LDS garbage -> absmax 2e29);
// (2) jlo8 clamped to <=160 so sG indices stay <104 and relvT reads stay
// inside the row (no dependence on benign workspace poison).

typedef __attribute__((ext_vector_type(8))) short short8;
typedef __attribute__((ext_vector_type(4))) float f32x4;

__device__ __forceinline__ float bf16f(unsigned int u) {
    union { unsigned int i; float f; } v; v.i = u << 16; return v.f;
}
__device__ __forceinline__ unsigned short f2b(float x) {
    __hip_bfloat16 h = __float2bfloat16(x);
    return *reinterpret_cast<unsigned short*>(&h);
}

// ---------------------------------------------------------------------------
// K0: prep.  z=0..4: split fp32 -> (hi,lo) bf16 for hs/Wq/Wk/Wv/Wo.
// z=5 (block 0): relkB bf16 [272][64], relvT bf16 relv^T [64][264].
// ---------------------------------------------------------------------------
__global__ __launch_bounds__(256) void k_prep(
    const float* __restrict__ hs, const float* __restrict__ Wq,
    const float* __restrict__ Wk, const float* __restrict__ Wv,
    const float* __restrict__ Wo, const float* __restrict__ relk,
    const float* __restrict__ relv,
    unsigned short* __restrict__ hh, unsigned short* __restrict__ hl,
    unsigned short* __restrict__ wqh, unsigned short* __restrict__ wql,
    unsigned short* __restrict__ wkh, unsigned short* __restrict__ wkl,
    unsigned short* __restrict__ wvh, unsigned short* __restrict__ wvl,
    unsigned short* __restrict__ woh, unsigned short* __restrict__ wol,
    unsigned short* __restrict__ relkB, unsigned short* __restrict__ relvT)
{
    const int z = blockIdx.y;
    const int tid = threadIdx.x;
    if (z < 5) {
        const float* src = (z == 0) ? hs : (z == 1) ? Wq : (z == 2) ? Wk
                         : (z == 3) ? Wv : Wo;
        unsigned short* hi = (z == 0) ? hh : (z == 1) ? wqh : (z == 2) ? wkh
                           : (z == 3) ? wvh : woh;
        unsigned short* lo = (z == 0) ? hl : (z == 1) ? wql : (z == 2) ? wkl
                           : (z == 3) ? wvl : wol;
        const int n4 = (z == 0) ? 1048576 : 262144;
        const int stride = gridDim.x * 256;
        for (int i = blockIdx.x * 256 + tid; i < n4; i += stride) {
            float4 x = *(const float4*)(src + i*4);
            unsigned short h[4], l[4];
            float xs[4] = {x.x, x.y, x.z, x.w};
            #pragma unroll
            for (int j = 0; j < 4; ++j) {
                h[j] = f2b(xs[j]);
                l[j] = f2b(xs[j] - bf16f(h[j]));
            }
            *(ushort4*)(hi + i*4) = make_ushort4(h[0], h[1], h[2], h[3]);
            *(ushort4*)(lo + i*4) = make_ushort4(l[0], l[1], l[2], l[3]);
        }
    } else if (blockIdx.x == 0) {
        for (int i = tid; i < 272*64; i += 256) {
            int j = i >> 6;
            relkB[i] = (j < 257) ? f2b(relk[i]) : (unsigned short)0;
        }
        int d = tid >> 2, grp = tid & 3;
        for (int jj = 0; jj < 66; ++jj) {
            int j = grp*66 + jj;
            if (j < 264)
                relvT[d*264 + j] = (j < 257) ? f2b(relv[j*64 + d]) : (unsigned short)0;
        }
    }
}

// ---------------------------------------------------------------------------
// K1: QKV projection via split-bf16 MFMA (unchanged).
// ---------------------------------------------------------------------------
__global__ __launch_bounds__(256) void k_gemm_qkv(
    const unsigned short* __restrict__ hh, const unsigned short* __restrict__ hl,
    const unsigned short* __restrict__ wqh, const unsigned short* __restrict__ wql,
    const unsigned short* __restrict__ wkh, const unsigned short* __restrict__ wkl,
    const unsigned short* __restrict__ wvh, const unsigned short* __restrict__ wvl,
    const float* __restrict__ bq, const float* __restrict__ bk,
    const float* __restrict__ bv,
    unsigned short* __restrict__ qb, unsigned short* __restrict__ kb,
    unsigned short* __restrict__ vt)
{
    __shared__ __align__(16) unsigned short sAh[128][48];
    __shared__ __align__(16) unsigned short sAl[128][48];
    __shared__ __align__(16) unsigned short sBh[128][48];
    __shared__ __align__(16) unsigned short sBl[128][48];
    const int tid = threadIdx.x;
    const int eb = blockIdx.x * 128, nb = blockIdx.y * 128, z = blockIdx.z;
    const unsigned short* Bh = (z == 0) ? wqh : (z == 1) ? wkh : wvh;
    const unsigned short* Bl = (z == 0) ? wql : (z == 1) ? wkl : wvl;
    const float* bias = (z == 0) ? bq : (z == 1) ? bk : bv;
    const float scale = (z == 0) ? 0.125f : 1.0f;
    const int w = tid >> 6, lane = tid & 63, lq = lane & 15, quad = lane >> 4;
    const int wr = w >> 1, wc = w & 1;
    const int srow = tid >> 2, sc8 = (tid & 3) * 8;

    f32x4 acc[4][4];
    #pragma unroll
    for (int i = 0; i < 4; ++i)
        #pragma unroll
        for (int j = 0; j < 4; ++j) acc[i][j] = (f32x4){0,0,0,0};

    for (int k0 = 0; k0 < 1024; k0 += 32) {
        uint4 a0h = *(const uint4*)(hh + (size_t)(nb + srow) * 1024 + k0 + sc8);
        uint4 a1h = *(const uint4*)(hh + (size_t)(nb + srow + 64) * 1024 + k0 + sc8);
        uint4 a0l = *(const uint4*)(hl + (size_t)(nb + srow) * 1024 + k0 + sc8);
        uint4 a1l = *(const uint4*)(hl + (size_t)(nb + srow + 64) * 1024 + k0 + sc8);
        uint4 b0h = *(const uint4*)(Bh + (size_t)(eb + srow) * 1024 + k0 + sc8);
        uint4 b1h = *(const uint4*)(Bh + (size_t)(eb + srow + 64) * 1024 + k0 + sc8);
        uint4 b0l = *(const uint4*)(Bl + (size_t)(eb + srow) * 1024 + k0 + sc8);
        uint4 b1l = *(const uint4*)(Bl + (size_t)(eb + srow + 64) * 1024 + k0 + sc8);
        __syncthreads();
        *(uint4*)&sAh[srow][sc8] = a0h;  *(uint4*)&sAh[srow + 64][sc8] = a1h;
        *(uint4*)&sAl[srow][sc8] = a0l;  *(uint4*)&sAl[srow + 64][sc8] = a1l;
        *(uint4*)&sBh[srow][sc8] = b0h;  *(uint4*)&sBh[srow + 64][sc8] = b1h;
        *(uint4*)&sBl[srow][sc8] = b0l;  *(uint4*)&sBl[srow + 64][sc8] = b1l;
        __syncthreads();

        short8 ah[4], al[4], bhf[4], blf[4];
        #pragma unroll
        for (int t = 0; t < 4; ++t) {
            ah[t]  = *(const short8*)&sAh[wr*64 + t*16 + lq][quad*8];
            al[t]  = *(const short8*)&sAl[wr*64 + t*16 + lq][quad*8];
            bhf[t] = *(const short8*)&sBh[wc*64 + t*16 + lq][quad*8];
            blf[t] = *(const short8*)&sBl[wc*64 + t*16 + lq][quad*8];
        }
        #pragma unroll
        for (int ti = 0; ti < 4; ++ti)
            #pragma unroll
            for (int tj = 0; tj < 4; ++tj) {
                acc[ti][tj] = __builtin_amdgcn_mfma_f32_16x16x32_bf16(ah[ti], bhf[tj], acc[ti][tj], 0, 0, 0);
                acc[ti][tj] = __builtin_amdgcn_mfma_f32_16x16x32_bf16(al[ti], bhf[tj], acc[ti][tj], 0, 0, 0);
                acc[ti][tj] = __builtin_amdgcn_mfma_f32_16x16x32_bf16(ah[ti], blf[tj], acc[ti][tj], 0, 0, 0);
            }
    }

    #pragma unroll
    for (int tj = 0; tj < 4; ++tj) {
        int e = eb + wc*64 + tj*16 + lq;
        float bb = bias[e];
        int h = e >> 6, d = e & 63;
        #pragma unroll
        for (int ti = 0; ti < 4; ++ti) {
            #pragma unroll
            for (int i = 0; i < 4; ++i) {
                int n = nb + wr*64 + ti*16 + quad*4 + i;
                int bidx = n >> 10, t = n & 1023;
                int s = bidx*16 + h;
                float val = (acc[ti][tj][i] + bb) * scale;
                if (z == 2)
                    vt[(((size_t)(s*64 + d)) << 10) + t] = f2b(val);
                else if (z == 0)
                    qb[(((size_t)(s*1024 + t)) << 6) + d] = f2b(val);
                else
                    kb[(((size_t)(s*1024 + t)) << 6) + d] = f2b(val);
            }
        }
    }
}

// ---------------------------------------------------------------------------
// K2: MFMA flash attention, 32 q-rows/block, prefetched K/V fragments.
// ---------------------------------------------------------------------------
__global__ __launch_bounds__(256) void k_fused(
    const unsigned short* __restrict__ qb, const unsigned short* __restrict__ kb,
    const unsigned short* __restrict__ vt, const unsigned short* __restrict__ relkB,
    const unsigned short* __restrict__ relvT, const float* __restrict__ relv,
    float* __restrict__ c1, float* __restrict__ c2)
{
    __shared__ __align__(16) unsigned short sP[2][2][16][72];  //  9216 B
    __shared__ __align__(16) unsigned short sG[2][16][104];    //  6656 B
    __shared__ unsigned short sR[32][273];                     // 17472 B
    __shared__ float sRed[4][3][32];                           //  1536 B

    const int tid = threadIdx.x;
    const int m  = blockIdx.y;
    const int q0 = blockIdx.x * 32;
    const int pm = (m & 15) * 4 + (m >> 4);
    const int m2 = (m & 3) * 16 + (m >> 2);
    const int w    = tid >> 6;
    const int lane = tid & 63;
    const int lq   = lane & 15;
    const int quad = lane >> 4;

    // ---- Phase A: R table via MFMA (32 rows) ----
    #pragma unroll
    for (int sub = 0; sub < 2; ++sub) {
        const unsigned short* qpm = qb + (((size_t)(pm*1024 + q0 + sub*16 + lq)) << 6);
        short8 a0 = *(const short8*)(qpm + quad*8);
        short8 a1 = *(const short8*)(qpm + 32 + quad*8);
        for (int jt = w; jt < 17; jt += 4) {
            const unsigned short* rkb = relkB + (size_t)(jt*16 + lq) * 64;
            short8 b0 = *(const short8*)(rkb + quad*8);
            short8 b1 = *(const short8*)(rkb + 32 + quad*8);
            f32x4 cr = {0,0,0,0};
            cr = __builtin_amdgcn_mfma_f32_16x16x32_bf16(a0, b0, cr, 0, 0, 0);
            cr = __builtin_amdgcn_mfma_f32_16x16x32_bf16(a1, b1, cr, 0, 0, 0);
            #pragma unroll
            for (int i = 0; i < 4; ++i)
                sR[sub*16 + quad*4 + i][jt*16 + lq] = f2b(cr[i]);
        }
    }
    __syncthreads();

    short8 aq0[2], aq1[2];
    #pragma unroll
    for (int sub = 0; sub < 2; ++sub) {
        const unsigned short* qm = qb + (((size_t)(m*1024 + q0 + sub*16 + lq)) << 6);
        aq0[sub] = *(const short8*)(qm + quad*8);
        aq1[sub] = *(const short8*)(qm + 32 + quad*8);
    }
    const float relE0 = relv[w*16 + lq];
    const float relE1 = relv[256*64 + w*16 + lq];

    float lsum[2][4], slow[2][4], shigh[2][4];
    f32x4 c1a[2], c2a[2];
    #pragma unroll
    for (int sub = 0; sub < 2; ++sub) {
        c1a[sub] = (f32x4){0,0,0,0};
        c2a[sub] = (f32x4){0,0,0,0};
        #pragma unroll
        for (int i = 0; i < 4; ++i) {
            lsum[sub][i] = 0.0f; slow[sub][i] = 0.0f; shigh[sub][i] = 0.0f;
        }
    }

    const unsigned short* kbase = kb + (((size_t)(m*1024 + w*16 + lq)) << 6);
    const unsigned short* vbase = vt + (((size_t)(m*64 + w*16 + lq)) << 10);
    short8 ck0 = *(const short8*)(kbase + quad*8);
    short8 ck1 = *(const short8*)(kbase + 32 + quad*8);
    short8 cv0 = *(const short8*)(vbase + quad*8);
    short8 cv1 = *(const short8*)(vbase + 32 + quad*8);

    #pragma unroll 1
    for (int kt = 0; kt < 16; ++kt) {
        const int k0 = kt * 64;
        const int dmin = q0 - k0 - 63;
        const int dmax = q0 + 31 - k0;
        const bool needG = (dmax >= -127) && (dmin <= 127);
        const int buf = kt & 1;

        // prefetch next tile's fragments (independent of current compute)
        short8 nk0 = ck0, nk1 = ck1, nv0 = cv0, nv1 = cv1;
        if (kt < 15) {
            const size_t ko = (size_t)(k0 + 64);
            nk0 = *(const short8*)(kbase + (ko << 6) + quad*8);
            nk1 = *(const short8*)(kbase + (ko << 6) + 32 + quad*8);
            nv0 = *(const short8*)(vbase + ko + quad*8);
            nv1 = *(const short8*)(vbase + ko + 32 + quad*8);
        }

        // ---- QK^T MFMA (K frags shared by both subtiles) ----
        f32x4 s4[2];
        #pragma unroll
        for (int sub = 0; sub < 2; ++sub) {
            s4[sub] = (f32x4){0,0,0,0};
            s4[sub] = __builtin_amdgcn_mfma_f32_16x16x32_bf16(aq0[sub], ck0, s4[sub], 0, 0, 0);
            s4[sub] = __builtin_amdgcn_mfma_f32_16x16x32_bf16(aq1[sub], ck1, s4[sub], 0, 0, 0);
        }

        // ---- exp + per-element edge accumulation ----
        const int kcol = k0 + w*16 + lq;
        float e[2][4];
        #pragma unroll
        for (int sub = 0; sub < 2; ++sub) {
            #pragma unroll
            for (int i = 0; i < 4; ++i) {
                int row = sub*16 + quad*4 + i;
                int dist = (q0 + row) - kcol;
                int jd = dist < -128 ? 0 : (dist > 128 ? 256 : dist + 128);
                float ev = exp2f((s4[sub][i] + bf16f(sR[row][jd])) * 1.44269504f);
                e[sub][i] = ev;
                lsum[sub][i] += ev;
                if (dist <= -128)     slow[sub][i]  += ev;
                else if (dist >= 128) shigh[sub][i] += ev;
                sP[buf][sub][quad*4 + i][w*16 + lq] = f2b(ev);
            }
        }
        if (needG) {
            // zero ALL of sG: 2*16*104 shorts = 1664 uints (R10 bug: 832)
            #pragma unroll
            for (int i = 0; i < 7; ++i) {
                int idx = tid + i * 256;
                if (idx < 1664) ((unsigned int*)sG)[idx] = 0u;
            }
        }
        __syncthreads();   // A: sP (+ zeroed sG) visible

        // band writes into sG direct from registers
        if (needG) {
            #pragma unroll
            for (int sub = 0; sub < 2; ++sub) {
                int jminb = q0 + sub*16 - k0 - 63;
                jminb = (jminb < -127 ? -127 : jminb) + 128;
                int jlo8 = jminb & ~7;
                if (jlo8 > 160) jlo8 = 160;   // window [jlo8, jlo8+95] within [0,255]
                #pragma unroll
                for (int i = 0; i < 4; ++i) {
                    int row = sub*16 + quad*4 + i;
                    int dist = (q0 + row) - kcol;
                    if (dist > -128 && dist < 128)
                        sG[sub][quad*4 + i][dist + 128 - jlo8] = f2b(e[sub][i]);
                }
            }
        }

        // ---- P·V MFMA ----
        #pragma unroll
        for (int sub = 0; sub < 2; ++sub) {
            short8 ap0 = *(const short8*)&sP[buf][sub][lq][quad*8];
            short8 ap1 = *(const short8*)&sP[buf][sub][lq][32 + quad*8];
            c1a[sub] = __builtin_amdgcn_mfma_f32_16x16x32_bf16(ap0, cv0, c1a[sub], 0, 0, 0);
            c1a[sub] = __builtin_amdgcn_mfma_f32_16x16x32_bf16(ap1, cv1, c1a[sub], 0, 0, 0);
        }

        if (needG) {
            __syncthreads();   // B: sG complete
            #pragma unroll
            for (int sub = 0; sub < 2; ++sub) {
                int jminb = q0 + sub*16 - k0 - 63;
                jminb = (jminb < -127 ? -127 : jminb) + 128;
                int jlo8 = jminb & ~7;
                if (jlo8 > 160) jlo8 = 160;
                short8 ag0 = *(const short8*)&sG[sub][lq][quad*8];
                short8 ag1 = *(const short8*)&sG[sub][lq][32 + quad*8];
                short8 ag2 = *(const short8*)&sG[sub][lq][64 + quad*8];
                const unsigned short* rrow = relvT + (size_t)(w*16 + lq) * 264 + jlo8;
                short8 br0 = *(const short8*)(rrow + quad*8);
                short8 br1 = *(const short8*)(rrow + 32 + quad*8);
                short8 br2 = *(const short8*)(rrow + 64 + quad*8);
                c2a[sub] = __builtin_amdgcn_mfma_f32_16x16x32_bf16(ag0, br0, c2a[sub], 0, 0, 0);
                c2a[sub] = __builtin_amdgcn_mfma_f32_16x16x32_bf16(ag1, br1, c2a[sub], 0, 0, 0);
                c2a[sub] = __builtin_amdgcn_mfma_f32_16x16x32_bf16(ag2, br2, c2a[sub], 0, 0, 0);
            }
            __syncthreads();   // C: protect sG before next tile's zero
        }

        ck0 = nk0; ck1 = nk1; cv0 = nv0; cv1 = nv1;
    }

    // ---- final reductions ----
    #pragma unroll
    for (int off = 1; off < 16; off <<= 1) {
        #pragma unroll
        for (int sub = 0; sub < 2; ++sub)
            #pragma unroll
            for (int i = 0; i < 4; ++i) {
                lsum[sub][i]  += __shfl_xor(lsum[sub][i],  off, 64);
                slow[sub][i]  += __shfl_xor(slow[sub][i],  off, 64);
                shigh[sub][i] += __shfl_xor(shigh[sub][i], off, 64);
            }
    }
    if (lq == 0) {
        #pragma unroll
        for (int sub = 0; sub < 2; ++sub)
            #pragma unroll
            for (int i = 0; i < 4; ++i) {
                int row = sub*16 + quad*4 + i;
                sRed[w][0][row] = lsum[sub][i];
                sRed[w][1][row] = slow[sub][i];
                sRed[w][2][row] = shigh[sub][i];
            }
    }
    __syncthreads();

    const int b1 = m >> 4,  h1 = m & 15;
    const int b2 = m2 >> 4, h2 = m2 & 15;
    #pragma unroll
    for (int sub = 0; sub < 2; ++sub) {
        #pragma unroll
        for (int i = 0; i < 4; ++i) {
            int row = sub*16 + quad*4 + i;
            float lt = sRed[0][0][row] + sRed[1][0][row] + sRed[2][0][row] + sRed[3][0][row];
            float sl = sRed[0][1][row] + sRed[1][1][row] + sRed[2][1][row] + sRed[3][1][row];
            float sh = sRed[0][2][row] + sRed[1][2][row] + sRed[2][2][row] + sRed[3][2][row];
            float c2v = c2a[sub][i] + sl * relE0 + sh * relE1;
            float inv = 1.0f / lt;
            int col = w*16 + lq;
            c1[(size_t)(b1*1024 + q0 + row) * 1024 + h1*64 + col] = c1a[sub][i] * inv;
            c2[(size_t)(b2*1024 + q0 + row) * 1024 + h2*64 + col] = c2v * inv;
        }
    }
}

// ---------------------------------------------------------------------------
// K3: out = (c1+c2) @ Wo^T + bo via split-bf16 MFMA (unchanged).
// ---------------------------------------------------------------------------
__global__ __launch_bounds__(256) void k_gemm_o(
    const float* __restrict__ c1, const float* __restrict__ c2,
    const unsigned short* __restrict__ woh, const unsigned short* __restrict__ wol,
    const float* __restrict__ bo, float* __restrict__ outp)
{
    __shared__ __align__(16) unsigned short sAh[128][48];
    __shared__ __align__(16) unsigned short sAl[128][48];
    __shared__ __align__(16) unsigned short sBh[128][48];
    __shared__ __align__(16) unsigned short sBl[128][48];
    const int tid = threadIdx.x;
    const int eb = blockIdx.x * 128, nb = blockIdx.y * 128;
    const int w = tid >> 6, lane = tid & 63, lq = lane & 15, quad = lane >> 4;
    const int wr = w >> 1, wc = w & 1;
    const int srow = tid >> 2, sc8 = (tid & 3) * 8;

    f32x4 acc[4][4];
    #pragma unroll
    for (int i = 0; i < 4; ++i)
        #pragma unroll
        for (int j = 0; j < 4; ++j) acc[i][j] = (f32x4){0,0,0,0};

    for (int k0 = 0; k0 < 1024; k0 += 32) {
        float av[2][8];
        #pragma unroll
        for (int r2 = 0; r2 < 2; ++r2) {
            size_t off = (size_t)(nb + srow + r2*64) * 1024 + k0 + sc8;
            float4 x0 = *(const float4*)(c1 + off);
            float4 x1 = *(const float4*)(c1 + off + 4);
            float4 y0 = *(const float4*)(c2 + off);
            float4 y1 = *(const float4*)(c2 + off + 4);
            av[r2][0] = x0.x + y0.x; av[r2][1] = x0.y + y0.y;
            av[r2][2] = x0.z + y0.z; av[r2][3] = x0.w + y0.w;
            av[r2][4] = x1.x + y1.x; av[r2][5] = x1.y + y1.y;
            av[r2][6] = x1.z + y1.z; av[r2][7] = x1.w + y1.w;
        }
        uint4 b0h = *(const uint4*)(woh + (size_t)(eb + srow) * 1024 + k0 + sc8);
        uint4 b1h = *(const uint4*)(woh + (size_t)(eb + srow + 64) * 1024 + k0 + sc8);
        uint4 b0l = *(const uint4*)(wol + (size_t)(eb + srow) * 1024 + k0 + sc8);
        uint4 b1l = *(const uint4*)(wol + (size_t)(eb + srow + 64) * 1024 + k0 + sc8);
        __syncthreads();
        #pragma unroll
        for (int r2 = 0; r2 < 2; ++r2) {
            unsigned short hh8[8], ll8[8];
            #pragma unroll
            for (int j = 0; j < 8; ++j) {
                hh8[j] = f2b(av[r2][j]);
                ll8[j] = f2b(av[r2][j] - bf16f(hh8[j]));
            }
            *(uint4*)&sAh[srow + r2*64][sc8] = *(const uint4*)hh8;
            *(uint4*)&sAl[srow + r2*64][sc8] = *(const uint4*)ll8;
        }
        *(uint4*)&sBh[srow][sc8] = b0h;  *(uint4*)&sBh[srow + 64][sc8] = b1h;
        *(uint4*)&sBl[srow][sc8] = b0l;  *(uint4*)&sBl[srow + 64][sc8] = b1l;
        __syncthreads();

        short8 ah[4], al[4], bhf[4], blf[4];
        #pragma unroll
        for (int t = 0; t < 4; ++t) {
            ah[t]  = *(const short8*)&sAh[wr*64 + t*16 + lq][quad*8];
            al[t]  = *(const short8*)&sAl[wr*64 + t*16 + lq][quad*8];
            bhf[t] = *(const short8*)&sBh[wc*64 + t*16 + lq][quad*8];
            blf[t] = *(const short8*)&sBl[wc*64 + t*16 + lq][quad*8];
        }
        #pragma unroll
        for (int ti = 0; ti < 4; ++ti)
            #pragma unroll
            for (int tj = 0; tj < 4; ++tj) {
                acc[ti][tj] = __builtin_amdgcn_mfma_f32_16x16x32_bf16(ah[ti], bhf[tj], acc[ti][tj], 0, 0, 0);
                acc[ti][tj] = __builtin_amdgcn_mfma_f32_16x16x32_bf16(al[ti], bhf[tj], acc[ti][tj], 0, 0, 0);
                acc[ti][tj] = __builtin_amdgcn_mfma_f32_16x16x32_bf16(ah[ti], blf[tj], acc[ti][tj], 0, 0, 0);
            }
    }

    #pragma unroll
    for (int tj = 0; tj < 4; ++tj) {
        int e = eb + wc*64 + tj*16 + lq;
        float bb = bo[e];
        #pragma unroll
        for (int ti = 0; ti < 4; ++ti) {
            #pragma unroll
            for (int i = 0; i < 4; ++i) {
                int n = nb + wr*64 + ti*16 + quad*4 + i;
                outp[(size_t)n * 1024 + e] = acc[ti][tj][i] + bb;
            }
        }
    }
}

// ---------------------------------------------------------------------------
extern "C" void kernel_launch(void* const* d_in, const int* in_sizes, int n_in,
                              void* d_out, int out_size, void* d_ws, size_t ws_size,
                              hipStream_t stream) {
    const float* hs   = (const float*)d_in[0];
    const float* Wq   = (const float*)d_in[1];
    const float* bq   = (const float*)d_in[2];
    const float* Wk   = (const float*)d_in[3];
    const float* bk   = (const float*)d_in[4];
    const float* Wv   = (const float*)d_in[5];
    const float* bv   = (const float*)d_in[6];
    const float* Wo   = (const float*)d_in[7];
    const float* bo   = (const float*)d_in[8];
    const float* relk = (const float*)d_in[9];
    const float* relv = (const float*)d_in[10];
    float* out = (float*)d_out;

    unsigned short* wsu = (unsigned short*)d_ws;
    unsigned short* qbp   = wsu;
    unsigned short* kbp   = wsu + 4194304;
    unsigned short* vtp   = wsu + 8388608;
    unsigned short* relkB = wsu + 12582912;
    unsigned short* relvT = wsu + 12600320;
    float* c1 = (float*)(wsu + 12617360);
    float* c2 = c1 + 4194304;
    unsigned short* hh  = wsu + 29394576;
    unsigned short* hl  = hh + 4194304;
    unsigned short* wqh = hl + 4194304;
    unsigned short* wql = wqh + 1048576;
    unsigned short* wkh = wql + 1048576;
    unsigned short* wkl = wkh + 1048576;
    unsigned short* wvh = wkl + 1048576;
    unsigned short* wvl = wvh + 1048576;
    unsigned short* woh = wvl + 1048576;
    unsigned short* wol = woh + 1048576;

    k_prep<<<dim3(512, 6), 256, 0, stream>>>(hs, Wq, Wk, Wv, Wo, relk, relv,
                                             hh, hl, wqh, wql, wkh, wkl,
                                             wvh, wvl, woh, wol, relkB, relvT);
    k_gemm_qkv<<<dim3(8, 32, 3), 256, 0, stream>>>(hh, hl, wqh, wql, wkh, wkl,
                                                   wvh, wvl, bq, bk, bv,
                                                   qbp, kbp, vtp);
    k_fused<<<dim3(32, 64), 256, 0, stream>>>(qbp, kbp, vtp, relkB, relvT, relv, c1, c2);
    k_gemm_o<<<dim3(8, 32), 256, 0, stream>>>(c1, c2, woh, wol, bo, out);
}